// Round 1
// baseline (1249.943 us; speedup 1.0000x reference)
//
#include <hip/hip_runtime.h>
#include <hip/hip_bf16.h>

// Shapes (compile-time constants)
#define DIM      1024
#define D_STATE  16
#define D_CONV   4
#define D_INNER  2048
#define DT_RANK  64
#define BATCH    2
#define SEQ      1024
#define MROWS    (BATCH * SEQ)          // 2048
#define NPROJ    (2 * D_INNER)          // 4096
#define XDBL_K   (DT_RANK + 2 * D_STATE) // 96

// ---------------------------------------------------------------------------
// Generic fp32 GEMM: C[m][n] = sum_k A[m][k] * B[n][k]   (both K-contiguous)
// EPI==1: C = softplus(C + bias[n])
// ---------------------------------------------------------------------------
template <int BM, int BN, int BK, int TM, int TN, int EPI>
__global__ __launch_bounds__(256) void gemm_nt(
    const float* __restrict__ A, int lda,
    const float* __restrict__ B, int ldb,
    float* __restrict__ C, int ldc,
    const float* __restrict__ bias,
    int M, int N, int K)
{
    constexpr int AS = BM + 4;
    constexpr int BS = BN + 4;
    __shared__ float As[BK][AS];
    __shared__ float Bs[BK][BS];

    const int tid = threadIdx.x;
    const int tx = tid & 15;        // n direction, 16 wide
    const int ty = tid >> 4;        // m direction, 16 wide
    const int m0 = blockIdx.y * BM;
    const int n0 = blockIdx.x * BN;

    float acc[TM][TN];
#pragma unroll
    for (int i = 0; i < TM; ++i)
#pragma unroll
        for (int j = 0; j < TN; ++j) acc[i][j] = 0.f;

    for (int k0 = 0; k0 < K; k0 += BK) {
        // Stage A tile (BM x BK), transposed into As[k][m]
#pragma unroll 1
        for (int idx = tid; idx < BM * BK / 4; idx += 256) {
            const int row = idx / (BK / 4);
            const int k4 = (idx % (BK / 4)) * 4;
            const float4 v = *reinterpret_cast<const float4*>(
                &A[(size_t)(m0 + row) * lda + k0 + k4]);
            As[k4 + 0][row] = v.x;
            As[k4 + 1][row] = v.y;
            As[k4 + 2][row] = v.z;
            As[k4 + 3][row] = v.w;
        }
        // Stage B tile (BN x BK), transposed into Bs[k][n]
#pragma unroll 1
        for (int idx = tid; idx < BN * BK / 4; idx += 256) {
            const int row = idx / (BK / 4);
            const int k4 = (idx % (BK / 4)) * 4;
            const float4 v = *reinterpret_cast<const float4*>(
                &B[(size_t)(n0 + row) * ldb + k0 + k4]);
            Bs[k4 + 0][row] = v.x;
            Bs[k4 + 1][row] = v.y;
            Bs[k4 + 2][row] = v.z;
            Bs[k4 + 3][row] = v.w;
        }
        __syncthreads();

#pragma unroll
        for (int kk = 0; kk < BK; ++kk) {
            float a[TM], b[TN];
#pragma unroll
            for (int i = 0; i < TM; ++i) a[i] = As[kk][ty * TM + i];
#pragma unroll
            for (int j = 0; j < TN; ++j) b[j] = Bs[kk][tx * TN + j];
#pragma unroll
            for (int i = 0; i < TM; ++i)
#pragma unroll
                for (int j = 0; j < TN; ++j)
                    acc[i][j] = fmaf(a[i], b[j], acc[i][j]);
        }
        __syncthreads();
    }

#pragma unroll
    for (int i = 0; i < TM; ++i) {
        const int m = m0 + ty * TM + i;
#pragma unroll
        for (int j = 0; j < TN; ++j) {
            const int n = n0 + tx * TN + j;
            float v = acc[i][j];
            if constexpr (EPI == 1) {
                v += bias[n];
                // stable softplus
                v = (v > 20.f) ? v : log1pf(__expf(v));
            }
            C[(size_t)m * ldc + n] = v;
        }
    }
}

// ---------------------------------------------------------------------------
// Causal depthwise conv (k=4) + bias + SiLU.
// Reads xx half of XR (cols 0..D_INNER-1), writes U[(b*L+l)][d].
// ---------------------------------------------------------------------------
__global__ __launch_bounds__(256) void conv_silu_kernel(
    const float* __restrict__ XR, const float* __restrict__ cw,
    const float* __restrict__ cb, float* __restrict__ U)
{
    const int idx = blockIdx.x * 256 + threadIdx.x;   // over MROWS*D_INNER
    const int d = idx & (D_INNER - 1);
    const int m = idx >> 11;              // b*SEQ + l
    const int l = m & (SEQ - 1);

    float acc = cb[d];
#pragma unroll
    for (int j = 0; j < D_CONV; ++j) {
        const int ll = l - (D_CONV - 1) + j;
        if (ll >= 0) {
            acc = fmaf(XR[(size_t)(m - (D_CONV - 1) + j) * NPROJ + d],
                       cw[d * D_CONV + j], acc);
        }
    }
    const float s = acc / (1.f + __expf(-acc));   // SiLU
    U[idx] = s;
}

// ---------------------------------------------------------------------------
// Selective scan. One block = one batch x 16 channels. thread=(d_local, n).
// Fuses +u*D and *silu(res) into the Y write.
// ---------------------------------------------------------------------------
__global__ __launch_bounds__(256) void scan_kernel(
    const float* __restrict__ DELTA, const float* __restrict__ U,
    const float* __restrict__ XDBL, const float* __restrict__ XR,
    const float* __restrict__ A_log, const float* __restrict__ Dp,
    float* __restrict__ Y)
{
    const int tid = threadIdx.x;
    const int n = tid & 15;
    const int dl = tid >> 4;
    const int bz = blockIdx.x;                 // 0..255
    const int b = bz >> 7;                     // 0..1
    const int dg = bz & 127;                   // 0..127
    const int d = dg * 16 + dl;

    const float a = -__expf(A_log[d * D_STATE + n]);
    const float Dd = Dp[d];
    float h = 0.f;
    const size_t base = (size_t)b * SEQ;

    for (int l = 0; l < SEQ; ++l) {
        const size_t m = base + l;
        const float delta = DELTA[m * D_INNER + d];
        const float u = U[m * D_INNER + d];
        const float Bv = XDBL[m * XDBL_K + DT_RANK + n];
        const float Cv = XDBL[m * XDBL_K + DT_RANK + D_STATE + n];

        const float dA = __expf(delta * a);
        h = fmaf(dA, h, delta * Bv * u);
        float p = h * Cv;
        // reduce over n (16 lanes, masks stay inside the group)
        p += __shfl_xor(p, 1);
        p += __shfl_xor(p, 2);
        p += __shfl_xor(p, 4);
        p += __shfl_xor(p, 8);

        if (n == 0) {
            float y = p + u * Dd;
            const float r = XR[m * NPROJ + D_INNER + d];
            const float sr = r / (1.f + __expf(-r));  // silu(res)
            Y[m * D_INNER + d] = y * sr;
        }
    }
}

// ---------------------------------------------------------------------------
extern "C" void kernel_launch(void* const* d_in, const int* in_sizes, int n_in,
                              void* d_out, int out_size, void* d_ws, size_t ws_size,
                              hipStream_t stream)
{
    const float* x       = (const float*)d_in[0];
    const float* in_w    = (const float*)d_in[1];
    const float* conv_w  = (const float*)d_in[2];
    const float* conv_b  = (const float*)d_in[3];
    const float* xproj_w = (const float*)d_in[4];
    const float* dt_w    = (const float*)d_in[5];
    const float* dt_b    = (const float*)d_in[6];
    const float* A_log   = (const float*)d_in[7];
    const float* Dp      = (const float*)d_in[8];
    const float* out_w   = (const float*)d_in[9];
    float* out = (float*)d_out;

    float* XR    = (float*)d_ws;                       // MROWS x NPROJ
    float* U     = XR + (size_t)MROWS * NPROJ;         // MROWS x D_INNER
    float* DELTA = U + (size_t)MROWS * D_INNER;        // MROWS x D_INNER
    float* XDBL  = DELTA + (size_t)MROWS * D_INNER;    // MROWS x XDBL_K
    float* Y     = XDBL + (size_t)MROWS * XDBL_K;      // MROWS x D_INNER

    const dim3 blk(256);

    // 1) XR = X @ in_w^T   (2048 x 4096, K=1024)
    gemm_nt<64, 64, 16, 4, 4, 0><<<dim3(NPROJ / 64, MROWS / 64), blk, 0, stream>>>(
        x, DIM, in_w, DIM, XR, NPROJ, nullptr, MROWS, NPROJ, DIM);

    // 2) U = silu(causal_conv(xx) + conv_b)
    conv_silu_kernel<<<(MROWS * D_INNER) / 256, blk, 0, stream>>>(XR, conv_w, conv_b, U);

    // 3) XDBL = U @ xproj_w^T   (2048 x 96, K=2048)
    gemm_nt<64, 32, 16, 4, 2, 0><<<dim3(XDBL_K / 32, MROWS / 64), blk, 0, stream>>>(
        U, D_INNER, xproj_w, D_INNER, XDBL, XDBL_K, nullptr, MROWS, XDBL_K, D_INNER);

    // 4) DELTA = softplus(XDBL[:, :64] @ dt_w^T + dt_b)  (2048 x 2048, K=64)
    gemm_nt<64, 64, 16, 4, 4, 1><<<dim3(D_INNER / 64, MROWS / 64), blk, 0, stream>>>(
        XDBL, XDBL_K, dt_w, DT_RANK, DELTA, D_INNER, dt_b, MROWS, D_INNER, DT_RANK);

    // 5) selective scan fused with +u*D and *silu(res)
    scan_kernel<<<BATCH * (D_INNER / 16), blk, 0, stream>>>(
        DELTA, U, XDBL, XR, A_log, Dp, Y);

    // 6) out = Y @ out_w^T   (2048 x 1024, K=2048)
    gemm_nt<64, 64, 16, 4, 4, 0><<<dim3(DIM / 64, MROWS / 64), blk, 0, stream>>>(
        Y, D_INNER, out_w, D_INNER, out, DIM, nullptr, MROWS, DIM, D_INNER);
}

// Round 2
// 682.007 us; speedup vs baseline: 1.8327x; 1.8327x over previous
//
#include <hip/hip_runtime.h>
#include <hip/hip_bf16.h>

// Shapes (compile-time constants)
#define DIM      1024
#define D_STATE  16
#define D_CONV   4
#define D_INNER  2048
#define DT_RANK  64
#define BATCH    2
#define SEQ      1024
#define MROWS    (BATCH * SEQ)          // 2048
#define NPROJ    (2 * D_INNER)          // 4096
#define XDBL_K   (DT_RANK + 2 * D_STATE) // 96

// chunked scan params
#define LC       16                      // steps per chunk
#define NC       (SEQ / LC)              // 64 chunks
#define SLANES   (BATCH * D_INNER * D_STATE) // 65536 state lanes

// ---------------------------------------------------------------------------
// Generic fp32 GEMM: C[m][n] = sum_k A[m][k] * B[n][k]   (both K-contiguous)
// EPI==1: C = softplus(C + bias[n])
// ---------------------------------------------------------------------------
template <int BM, int BN, int BK, int TM, int TN, int EPI>
__global__ __launch_bounds__(256) void gemm_nt(
    const float* __restrict__ A, int lda,
    const float* __restrict__ B, int ldb,
    float* __restrict__ C, int ldc,
    const float* __restrict__ bias,
    int M, int N, int K)
{
    constexpr int AS = BM + 4;
    constexpr int BS = BN + 4;
    __shared__ float As[BK][AS];
    __shared__ float Bs[BK][BS];

    const int tid = threadIdx.x;
    const int tx = tid & 15;        // n direction, 16 wide
    const int ty = tid >> 4;        // m direction, 16 wide
    const int m0 = blockIdx.y * BM;
    const int n0 = blockIdx.x * BN;

    float acc[TM][TN];
#pragma unroll
    for (int i = 0; i < TM; ++i)
#pragma unroll
        for (int j = 0; j < TN; ++j) acc[i][j] = 0.f;

    for (int k0 = 0; k0 < K; k0 += BK) {
#pragma unroll 1
        for (int idx = tid; idx < BM * BK / 4; idx += 256) {
            const int row = idx / (BK / 4);
            const int k4 = (idx % (BK / 4)) * 4;
            const float4 v = *reinterpret_cast<const float4*>(
                &A[(size_t)(m0 + row) * lda + k0 + k4]);
            As[k4 + 0][row] = v.x;
            As[k4 + 1][row] = v.y;
            As[k4 + 2][row] = v.z;
            As[k4 + 3][row] = v.w;
        }
#pragma unroll 1
        for (int idx = tid; idx < BN * BK / 4; idx += 256) {
            const int row = idx / (BK / 4);
            const int k4 = (idx % (BK / 4)) * 4;
            const float4 v = *reinterpret_cast<const float4*>(
                &B[(size_t)(n0 + row) * ldb + k0 + k4]);
            Bs[k4 + 0][row] = v.x;
            Bs[k4 + 1][row] = v.y;
            Bs[k4 + 2][row] = v.z;
            Bs[k4 + 3][row] = v.w;
        }
        __syncthreads();

#pragma unroll
        for (int kk = 0; kk < BK; ++kk) {
            float a[TM], b[TN];
#pragma unroll
            for (int i = 0; i < TM; ++i) a[i] = As[kk][ty * TM + i];
#pragma unroll
            for (int j = 0; j < TN; ++j) b[j] = Bs[kk][tx * TN + j];
#pragma unroll
            for (int i = 0; i < TM; ++i)
#pragma unroll
                for (int j = 0; j < TN; ++j)
                    acc[i][j] = fmaf(a[i], b[j], acc[i][j]);
        }
        __syncthreads();
    }

#pragma unroll
    for (int i = 0; i < TM; ++i) {
        const int m = m0 + ty * TM + i;
#pragma unroll
        for (int j = 0; j < TN; ++j) {
            const int n = n0 + tx * TN + j;
            float v = acc[i][j];
            if constexpr (EPI == 1) {
                v += bias[n];
                v = (v > 20.f) ? v : log1pf(__expf(v));
            }
            C[(size_t)m * ldc + n] = v;
        }
    }
}

// ---------------------------------------------------------------------------
// Causal depthwise conv (k=4) + bias + SiLU.
// ---------------------------------------------------------------------------
__global__ __launch_bounds__(256) void conv_silu_kernel(
    const float* __restrict__ XR, const float* __restrict__ cw,
    const float* __restrict__ cb, float* __restrict__ U)
{
    const int idx = blockIdx.x * 256 + threadIdx.x;   // over MROWS*D_INNER
    const int d = idx & (D_INNER - 1);
    const int m = idx >> 11;              // b*SEQ + l
    const int l = m & (SEQ - 1);

    float acc = cb[d];
#pragma unroll
    for (int j = 0; j < D_CONV; ++j) {
        const int ll = l - (D_CONV - 1) + j;
        if (ll >= 0) {
            acc = fmaf(XR[(size_t)(m - (D_CONV - 1) + j) * NPROJ + d],
                       cw[d * D_CONV + j], acc);
        }
    }
    const float s = acc / (1.f + __expf(-acc));   // SiLU
    U[idx] = s;
}

// ---------------------------------------------------------------------------
// Chunked selective scan.
// Phase 1: per (b, 16-channel group, chunk): local scan with h0=0.
//          Stores P = prod(dA) and HL = local final state, per (b,d,n).
// ---------------------------------------------------------------------------
__global__ __launch_bounds__(256) void scan_phase1(
    const float* __restrict__ DELTA, const float* __restrict__ U,
    const float* __restrict__ XDBL, const float* __restrict__ A_log,
    float* __restrict__ P, float* __restrict__ HL)
{
    const int tid = threadIdx.x;
    const int n = tid & 15;
    const int dl = tid >> 4;
    const int g = blockIdx.x;                  // 0..255
    const int b = g >> 7;
    const int dg = g & 127;
    const int d = dg * 16 + dl;
    const int c = blockIdx.y;                  // chunk

    const float a = -__expf(A_log[d * D_STATE + n]);
    float h = 0.f;
    float p = 1.f;
    const size_t base = (size_t)b * SEQ + c * LC;

#pragma unroll
    for (int t = 0; t < LC; ++t) {
        const size_t m = base + t;
        const float delta = DELTA[m * D_INNER + d];
        const float u = U[m * D_INNER + d];
        const float Bv = XDBL[m * XDBL_K + DT_RANK + n];
        const float dA = __expf(delta * a);
        h = fmaf(dA, h, delta * Bv * u);
        p *= dA;
    }
    const size_t idx = (size_t)c * SLANES + ((size_t)b * D_INNER + d) * D_STATE + n;
    P[idx] = p;
    HL[idx] = h;
}

// ---------------------------------------------------------------------------
// Phase 2: scan over chunk states. One thread per (b,d,n) state lane.
// Overwrites P[c] with H0[c] (state at chunk start). Read-before-write per
// element by the same thread, so in-place is safe.
// ---------------------------------------------------------------------------
__global__ __launch_bounds__(256) void scan_phase2(
    float* __restrict__ P, const float* __restrict__ HL)
{
    const int t = blockIdx.x * 256 + threadIdx.x;  // 0..SLANES-1
    float h = 0.f;
#pragma unroll
    for (int c = 0; c < NC; ++c) {
        const size_t idx = (size_t)c * SLANES + t;
        const float p = P[idx];
        const float hl = HL[idx];
        P[idx] = h;                 // H0 for chunk c
        h = fmaf(p, h, hl);
    }
}

// ---------------------------------------------------------------------------
// Phase 3: re-run each chunk from true H0; emit Y fused with +u*D, *silu(res).
// ---------------------------------------------------------------------------
__global__ __launch_bounds__(256) void scan_phase3(
    const float* __restrict__ DELTA, const float* __restrict__ U,
    const float* __restrict__ XDBL, const float* __restrict__ XR,
    const float* __restrict__ A_log, const float* __restrict__ Dp,
    const float* __restrict__ H0, float* __restrict__ Y)
{
    const int tid = threadIdx.x;
    const int n = tid & 15;
    const int dl = tid >> 4;
    const int g = blockIdx.x;
    const int b = g >> 7;
    const int dg = g & 127;
    const int d = dg * 16 + dl;
    const int c = blockIdx.y;

    const float a = -__expf(A_log[d * D_STATE + n]);
    const float Dd = Dp[d];
    float h = H0[(size_t)c * SLANES + ((size_t)b * D_INNER + d) * D_STATE + n];
    const size_t base = (size_t)b * SEQ + c * LC;

#pragma unroll
    for (int t = 0; t < LC; ++t) {
        const size_t m = base + t;
        const float delta = DELTA[m * D_INNER + d];
        const float u = U[m * D_INNER + d];
        const float Bv = XDBL[m * XDBL_K + DT_RANK + n];
        const float Cv = XDBL[m * XDBL_K + DT_RANK + D_STATE + n];

        const float dA = __expf(delta * a);
        h = fmaf(dA, h, delta * Bv * u);
        float pv = h * Cv;
        pv += __shfl_xor(pv, 1);
        pv += __shfl_xor(pv, 2);
        pv += __shfl_xor(pv, 4);
        pv += __shfl_xor(pv, 8);

        if (n == 0) {
            const float y = pv + u * Dd;
            const float r = XR[m * NPROJ + D_INNER + d];
            const float sr = r / (1.f + __expf(-r));
            Y[m * D_INNER + d] = y * sr;
        }
    }
}

// ---------------------------------------------------------------------------
extern "C" void kernel_launch(void* const* d_in, const int* in_sizes, int n_in,
                              void* d_out, int out_size, void* d_ws, size_t ws_size,
                              hipStream_t stream)
{
    const float* x       = (const float*)d_in[0];
    const float* in_w    = (const float*)d_in[1];
    const float* conv_w  = (const float*)d_in[2];
    const float* conv_b  = (const float*)d_in[3];
    const float* xproj_w = (const float*)d_in[4];
    const float* dt_w    = (const float*)d_in[5];
    const float* dt_b    = (const float*)d_in[6];
    const float* A_log   = (const float*)d_in[7];
    const float* Dp      = (const float*)d_in[8];
    const float* out_w   = (const float*)d_in[9];
    float* out = (float*)d_out;

    float* XR    = (float*)d_ws;                       // MROWS x NPROJ
    float* U     = XR + (size_t)MROWS * NPROJ;         // MROWS x D_INNER
    float* DELTA = U + (size_t)MROWS * D_INNER;        // MROWS x D_INNER
    float* XDBL  = DELTA + (size_t)MROWS * D_INNER;    // MROWS x XDBL_K
    float* Y     = XDBL + (size_t)MROWS * XDBL_K;      // MROWS x D_INNER
    float* Pbuf  = Y + (size_t)MROWS * D_INNER;        // NC x SLANES
    float* HLbuf = Pbuf + (size_t)NC * SLANES;         // NC x SLANES

    const dim3 blk(256);

    // 1) XR = X @ in_w^T   (2048 x 4096, K=1024)
    gemm_nt<64, 64, 16, 4, 4, 0><<<dim3(NPROJ / 64, MROWS / 64), blk, 0, stream>>>(
        x, DIM, in_w, DIM, XR, NPROJ, nullptr, MROWS, NPROJ, DIM);

    // 2) U = silu(causal_conv(xx) + conv_b)
    conv_silu_kernel<<<(MROWS * D_INNER) / 256, blk, 0, stream>>>(XR, conv_w, conv_b, U);

    // 3) XDBL = U @ xproj_w^T   (2048 x 96, K=2048)
    gemm_nt<64, 32, 16, 4, 2, 0><<<dim3(XDBL_K / 32, MROWS / 64), blk, 0, stream>>>(
        U, D_INNER, xproj_w, D_INNER, XDBL, XDBL_K, nullptr, MROWS, XDBL_K, D_INNER);

    // 4) DELTA = softplus(XDBL[:, :64] @ dt_w^T + dt_b)  (2048 x 2048, K=64)
    gemm_nt<64, 64, 16, 4, 4, 1><<<dim3(D_INNER / 64, MROWS / 64), blk, 0, stream>>>(
        XDBL, XDBL_K, dt_w, DT_RANK, DELTA, D_INNER, dt_b, MROWS, D_INNER, DT_RANK);

    // 5) chunked selective scan
    scan_phase1<<<dim3(BATCH * (D_INNER / 16), NC), blk, 0, stream>>>(
        DELTA, U, XDBL, A_log, Pbuf, HLbuf);
    scan_phase2<<<SLANES / 256, blk, 0, stream>>>(Pbuf, HLbuf);
    scan_phase3<<<dim3(BATCH * (D_INNER / 16), NC), blk, 0, stream>>>(
        DELTA, U, XDBL, XR, A_log, Dp, Pbuf, Y);

    // 6) out = Y @ out_w^T   (2048 x 1024, K=2048)
    gemm_nt<64, 64, 16, 4, 4, 0><<<dim3(DIM / 64, MROWS / 64), blk, 0, stream>>>(
        Y, D_INNER, out_w, D_INNER, out, DIM, nullptr, MROWS, DIM, D_INNER);
}

// Round 3
// 375.353 us; speedup vs baseline: 3.3300x; 1.8170x over previous
//
#include <hip/hip_runtime.h>
#include <hip/hip_bf16.h>
#include <stdint.h>

// Shapes
#define DIM      1024
#define D_STATE  16
#define D_CONV   4
#define D_INNER  2048
#define DT_RANK  64
#define BATCH    2
#define SEQ      1024
#define MROWS    (BATCH * SEQ)            // 2048
#define NPROJ    (2 * D_INNER)            // 4096
#define XDBL_K   (DT_RANK + 2 * D_STATE)  // 96

// chunked scan
#define LC       32
#define NC       (SEQ / LC)               // 32
#define SLANES   (BATCH * D_INNER * D_STATE) // 65536

typedef __attribute__((ext_vector_type(8))) short short8;
typedef __attribute__((ext_vector_type(4))) float f32x4;

__device__ __forceinline__ unsigned short f2bf(float f) {
    __hip_bfloat16 b = __float2bfloat16(f);
    return *reinterpret_cast<unsigned short*>(&b);
}
__device__ __forceinline__ float bf2f(unsigned short u) {
    __hip_bfloat16 b;
    *reinterpret_cast<unsigned short*>(&b) = u;
    return __bfloat162float(b);
}

__device__ __forceinline__ void gload_lds16(const unsigned short* g, unsigned short* l) {
    __builtin_amdgcn_global_load_lds(
        (const __attribute__((address_space(1))) void*)g,
        (__attribute__((address_space(3))) void*)l,
        16, 0, 0);
}

// ---------------------------------------------------------------------------
// 3-segment bf16 split. MODE 0 (A-side): [hi|hi|lo]. MODE 1 (B-side): [hi|lo|hi].
// Rows >= rows_src are zero-padded. dst row stride = 3K.
// ---------------------------------------------------------------------------
template <int MODE>
__global__ __launch_bounds__(256) void split3(
    const float* __restrict__ src, int lda, int K,
    unsigned short* __restrict__ dst, int rows_src)
{
    const int t = blockIdx.x * 256 + threadIdx.x;
    const int kq = K >> 2;
    const int r = t / kq;
    const int k4 = (t - r * kq) << 2;
    float4 v = make_float4(0.f, 0.f, 0.f, 0.f);
    if (r < rows_src)
        v = *reinterpret_cast<const float4*>(src + (size_t)r * lda + k4);
    const unsigned short h0 = f2bf(v.x), h1 = f2bf(v.y), h2 = f2bf(v.z), h3 = f2bf(v.w);
    const unsigned short l0 = f2bf(v.x - bf2f(h0)), l1 = f2bf(v.y - bf2f(h1));
    const unsigned short l2 = f2bf(v.z - bf2f(h2)), l3 = f2bf(v.w - bf2f(h3));
    const ushort4 hv = make_ushort4(h0, h1, h2, h3);
    const ushort4 lv = make_ushort4(l0, l1, l2, l3);
    unsigned short* dr = dst + (size_t)r * 3 * K + k4;
    *reinterpret_cast<ushort4*>(dr)         = hv;
    *reinterpret_cast<ushort4*>(dr + K)     = (MODE == 0) ? hv : lv;
    *reinterpret_cast<ushort4*>(dr + 2 * K) = (MODE == 0) ? lv : hv;
}

// ---------------------------------------------------------------------------
// bf16 MFMA GEMM (NT): C[m][n] = sum_k A[m][k]*B[n][k], fp32 accum.
// 128x128 tile, BK=64, 4 waves. global_load_lds(16B) staging with swizzled
// source cols; ds_read_b128 with matching XOR swizzle (conflict-free).
// blockIdx.z = split-K slice (kLen per slice), C += z*czstride.
// EPI 1: softplus(C + bias[n]).
// ---------------------------------------------------------------------------
__device__ __forceinline__ short8 frag_ld(const unsigned short* base, int row, int slot) {
    const char* p = reinterpret_cast<const char*>(base) +
                    row * 128 + (((slot ^ (row & 7)) & 7) << 4);
    return *reinterpret_cast<const short8*>(p);
}

template <int EPI>
__global__ __launch_bounds__(256) void gemm_mfma(
    const unsigned short* __restrict__ A, int lda,
    const unsigned short* __restrict__ B, int ldb,
    float* __restrict__ C, int ldc, size_t czstride,
    const float* __restrict__ bias, int kLen)
{
    __shared__ unsigned short As[128 * 64];
    __shared__ unsigned short Bs[128 * 64];

    const int tid = threadIdx.x;
    const int lane = tid & 63;
    const int w = tid >> 6;
    const int wr = w >> 1, wc = w & 1;
    const int fr = lane & 15, fg = lane >> 4;
    const int m0 = blockIdx.y * 128;
    const int n0 = blockIdx.x * 128;
    const int kOff = blockIdx.z * kLen;
    A += kOff;
    B += kOff;
    C += (size_t)blockIdx.z * czstride;

    f32x4 zero = {0.f, 0.f, 0.f, 0.f};
    f32x4 acc[4][4];
#pragma unroll
    for (int i = 0; i < 4; ++i)
#pragma unroll
        for (int j = 0; j < 4; ++j) acc[i][j] = zero;

    for (int k0 = 0; k0 < kLen; k0 += 64) {
#pragma unroll
        for (int it = 0; it < 4; ++it) {
            const int f = it * 256 + tid;
            const int row = f >> 3;
            const int gc = ((f & 7) ^ (row & 7)) << 3;   // swizzled source col (bf16)
            gload_lds16(A + (size_t)(m0 + row) * lda + k0 + gc, &As[f * 8]);
            gload_lds16(B + (size_t)(n0 + row) * ldb + k0 + gc, &Bs[f * 8]);
        }
        __syncthreads();
#pragma unroll
        for (int kk = 0; kk < 2; ++kk) {
            short8 af[4], bf_[4];
#pragma unroll
            for (int i = 0; i < 4; ++i) {
                af[i]  = frag_ld(As, wr * 64 + i * 16 + fr, kk * 4 + fg);
                bf_[i] = frag_ld(Bs, wc * 64 + i * 16 + fr, kk * 4 + fg);
            }
#pragma unroll
            for (int i = 0; i < 4; ++i)
#pragma unroll
                for (int j = 0; j < 4; ++j)
                    acc[i][j] = __builtin_amdgcn_mfma_f32_16x16x32_bf16(
                        af[i], bf_[j], acc[i][j], 0, 0, 0);
        }
        __syncthreads();
    }

#pragma unroll
    for (int i = 0; i < 4; ++i) {
        const int mrow = m0 + wr * 64 + i * 16 + fg * 4;
#pragma unroll
        for (int j = 0; j < 4; ++j) {
            const int col = n0 + wc * 64 + j * 16 + fr;
#pragma unroll
            for (int r = 0; r < 4; ++r) {
                float v = acc[i][j][r];
                if constexpr (EPI == 1) {
                    v += bias[col];
                    v = (v > 20.f) ? v : log1pf(__expf(v));
                }
                C[(size_t)(mrow + r) * ldc + col] = v;
            }
        }
    }
}

// ---------------------------------------------------------------------------
// Causal depthwise conv (k=4) + bias + SiLU; emits U (fp32) and split US.
// ---------------------------------------------------------------------------
__global__ __launch_bounds__(256) void conv_silu_split(
    const float* __restrict__ XR, const float* __restrict__ cw,
    const float* __restrict__ cb, float* __restrict__ U,
    unsigned short* __restrict__ US)
{
    const int idx = blockIdx.x * 256 + threadIdx.x;
    const int d = idx & (D_INNER - 1);
    const int m = idx >> 11;
    const int l = m & (SEQ - 1);

    float acc = cb[d];
#pragma unroll
    for (int j = 0; j < D_CONV; ++j) {
        const int ll = l - (D_CONV - 1) + j;
        if (ll >= 0)
            acc = fmaf(XR[(size_t)(m - (D_CONV - 1) + j) * NPROJ + d],
                       cw[d * D_CONV + j], acc);
    }
    const float s = acc / (1.f + __expf(-acc));
    U[idx] = s;
    const unsigned short h = f2bf(s);
    const unsigned short lo = f2bf(s - bf2f(h));
    const size_t rb = (size_t)m * (3 * D_INNER);
    US[rb + d] = h;
    US[rb + D_INNER + d] = h;
    US[rb + 2 * D_INNER + d] = lo;
}

// ---------------------------------------------------------------------------
// Chunked selective scan (LC=32)
// ---------------------------------------------------------------------------
__global__ __launch_bounds__(256) void scan_phase1(
    const float* __restrict__ DELTA, const float* __restrict__ U,
    const float* __restrict__ XDBL, const float* __restrict__ A_log,
    float* __restrict__ P, float* __restrict__ HL)
{
    const int tid = threadIdx.x;
    const int n = tid & 15;
    const int dl = tid >> 4;
    const int g = blockIdx.x;
    const int b = g >> 7;
    const int dg = g & 127;
    const int d = dg * 16 + dl;
    const int c = blockIdx.y;

    const float a = -__expf(A_log[d * D_STATE + n]);
    float h = 0.f;
    float p = 1.f;
    const size_t base = (size_t)b * SEQ + c * LC;

#pragma unroll 4
    for (int t = 0; t < LC; ++t) {
        const size_t m = base + t;
        const float delta = DELTA[m * D_INNER + d];
        const float u = U[m * D_INNER + d];
        const float Bv = XDBL[m * XDBL_K + DT_RANK + n];
        const float dA = __expf(delta * a);
        h = fmaf(dA, h, delta * Bv * u);
        p *= dA;
    }
    const size_t idx = (size_t)c * SLANES + ((size_t)b * D_INNER + d) * D_STATE + n;
    P[idx] = p;
    HL[idx] = h;
}

__global__ __launch_bounds__(256) void scan_phase2(
    float* __restrict__ P, const float* __restrict__ HL)
{
    const int t = blockIdx.x * 256 + threadIdx.x;
    float h = 0.f;
#pragma unroll
    for (int c = 0; c < NC; ++c) {
        const size_t idx = (size_t)c * SLANES + t;
        const float p = P[idx];
        const float hl = HL[idx];
        P[idx] = h;
        h = fmaf(p, h, hl);
    }
}

__global__ __launch_bounds__(256) void scan_phase3(
    const float* __restrict__ DELTA, const float* __restrict__ U,
    const float* __restrict__ XDBL, const float* __restrict__ XR,
    const float* __restrict__ A_log, const float* __restrict__ Dp,
    const float* __restrict__ H0, unsigned short* __restrict__ YS)
{
    const int tid = threadIdx.x;
    const int n = tid & 15;
    const int dl = tid >> 4;
    const int g = blockIdx.x;
    const int b = g >> 7;
    const int dg = g & 127;
    const int d = dg * 16 + dl;
    const int c = blockIdx.y;

    const float a = -__expf(A_log[d * D_STATE + n]);
    const float Dd = Dp[d];
    float h = H0[(size_t)c * SLANES + ((size_t)b * D_INNER + d) * D_STATE + n];
    const size_t base = (size_t)b * SEQ + c * LC;

#pragma unroll 4
    for (int t = 0; t < LC; ++t) {
        const size_t m = base + t;
        const float delta = DELTA[m * D_INNER + d];
        const float u = U[m * D_INNER + d];
        const float Bv = XDBL[m * XDBL_K + DT_RANK + n];
        const float Cv = XDBL[m * XDBL_K + DT_RANK + D_STATE + n];

        const float dA = __expf(delta * a);
        h = fmaf(dA, h, delta * Bv * u);
        float pv = h * Cv;
        pv += __shfl_xor(pv, 1);
        pv += __shfl_xor(pv, 2);
        pv += __shfl_xor(pv, 4);
        pv += __shfl_xor(pv, 8);

        if (n == 0) {
            const float y = pv + u * Dd;
            const float r = XR[m * NPROJ + D_INNER + d];
            const float sr = r / (1.f + __expf(-r));
            const float yg = y * sr;
            const unsigned short hh = f2bf(yg);
            const unsigned short lo = f2bf(yg - bf2f(hh));
            const size_t rb = m * (3 * D_INNER);
            YS[rb + d] = hh;
            YS[rb + D_INNER + d] = hh;
            YS[rb + 2 * D_INNER + d] = lo;
        }
    }
}

// ---------------------------------------------------------------------------
// split-K reductions
// ---------------------------------------------------------------------------
__global__ __launch_bounds__(256) void reduce_xdbl(
    const float* __restrict__ PP, float* __restrict__ XDBL)
{
    const int t = blockIdx.x * 256 + threadIdx.x;   // 0..2048*96-1
    const int m = t / XDBL_K;
    const int n = t - m * XDBL_K;
    float s = 0.f;
#pragma unroll
    for (int z = 0; z < 8; ++z)
        s += PP[(size_t)z * MROWS * 128 + (size_t)m * 128 + n];
    XDBL[t] = s;
}

__global__ __launch_bounds__(256) void reduce_out(
    const float* __restrict__ OP, float* __restrict__ out)
{
    const int t = blockIdx.x * 256 + threadIdx.x;   // x4 floats
    const float4 a = *reinterpret_cast<const float4*>(OP + (size_t)t * 4);
    const float4 b = *reinterpret_cast<const float4*>(OP + (size_t)MROWS * DIM + (size_t)t * 4);
    float4 r;
    r.x = a.x + b.x; r.y = a.y + b.y; r.z = a.z + b.z; r.w = a.w + b.w;
    *reinterpret_cast<float4*>(out + (size_t)t * 4) = r;
}

// ---------------------------------------------------------------------------
extern "C" void kernel_launch(void* const* d_in, const int* in_sizes, int n_in,
                              void* d_out, int out_size, void* d_ws, size_t ws_size,
                              hipStream_t stream)
{
    const float* x       = (const float*)d_in[0];
    const float* in_w    = (const float*)d_in[1];
    const float* conv_w  = (const float*)d_in[2];
    const float* conv_b  = (const float*)d_in[3];
    const float* xproj_w = (const float*)d_in[4];
    const float* dt_w    = (const float*)d_in[5];
    const float* dt_b    = (const float*)d_in[6];
    const float* A_log   = (const float*)d_in[7];
    const float* Dp      = (const float*)d_in[8];
    const float* out_w   = (const float*)d_in[9];
    float* out = (float*)d_out;

    const size_t MF = 1024 * 1024;
    float* WF    = (float*)d_ws;
    float* XR    = WF;                  // 8M floats [gemm1 out; conv; phase3 res; then OP]
    float* U     = WF + 8 * MF;         // 4M
    float* DELTA = WF + 12 * MF;        // 4M
    float* XDBL  = WF + 16 * MF;        // 0.19M
    float* R1    = WF + 17 * MF;        // 2M: PP -> P
    float* R2    = WF + 19 * MF;        // 2M: DS_A/DS_B -> HL
    unsigned short* SCRA = (unsigned short*)(WF + 21 * MF);  // XS -> US -> YS
    unsigned short* SCRB = (unsigned short*)(WF + 28 * MF);  // WS1 -> WS2 -> WS4
    float* PP = R1;
    float* P  = R1;
    float* HL = R2;
    unsigned short* DS_A = (unsigned short*)R2;
    unsigned short* DS_B = DS_A + (size_t)MROWS * 192;
    float* OP = XR;                     // out-GEMM partials (XR dead by then)

    const dim3 blk(256);

    // ---- in_proj: XR = X @ in_w^T ----
    split3<0><<<(MROWS * (DIM / 4)) / 256, blk, 0, stream>>>(x, DIM, DIM, SCRA, MROWS);
    split3<1><<<(NPROJ * (DIM / 4)) / 256, blk, 0, stream>>>(in_w, DIM, DIM, SCRB, NPROJ);
    gemm_mfma<0><<<dim3(NPROJ / 128, MROWS / 128, 1), blk, 0, stream>>>(
        SCRA, 3 * DIM, SCRB, 3 * DIM, XR, NPROJ, 0, nullptr, 3 * DIM);

    // ---- conv + silu (emits U fp32 + US split) ----
    conv_silu_split<<<(MROWS * D_INNER) / 256, blk, 0, stream>>>(XR, conv_w, conv_b, U, SCRA);

    // ---- x_dbl = U @ xproj_w^T (N padded 96->128, split-K=8) ----
    split3<1><<<(128 * (D_INNER / 4)) / 256, blk, 0, stream>>>(xproj_w, D_INNER, D_INNER, SCRB, XDBL_K);
    gemm_mfma<0><<<dim3(1, MROWS / 128, 8), blk, 0, stream>>>(
        SCRA, 3 * D_INNER, SCRB, 3 * D_INNER, PP, 128, (size_t)MROWS * 128, nullptr, (3 * D_INNER) / 8);
    reduce_xdbl<<<(MROWS * XDBL_K) / 256, blk, 0, stream>>>(PP, XDBL);

    // ---- DELTA = softplus(XDBL[:, :64] @ dt_w^T + dt_b) ----
    split3<0><<<(MROWS * (DT_RANK / 4)) / 256, blk, 0, stream>>>(XDBL, XDBL_K, DT_RANK, DS_A, MROWS);
    split3<1><<<(D_INNER * (DT_RANK / 4)) / 256, blk, 0, stream>>>(dt_w, DT_RANK, DT_RANK, DS_B, D_INNER);
    gemm_mfma<1><<<dim3(D_INNER / 128, MROWS / 128, 1), blk, 0, stream>>>(
        DS_A, 3 * DT_RANK, DS_B, 3 * DT_RANK, DELTA, D_INNER, 0, dt_b, 3 * DT_RANK);

    // ---- chunked selective scan (phase3 emits split YS) ----
    scan_phase1<<<dim3(BATCH * (D_INNER / 16), NC), blk, 0, stream>>>(
        DELTA, U, XDBL, A_log, P, HL);
    scan_phase2<<<SLANES / 256, blk, 0, stream>>>(P, HL);
    scan_phase3<<<dim3(BATCH * (D_INNER / 16), NC), blk, 0, stream>>>(
        DELTA, U, XDBL, XR, A_log, Dp, P, SCRA);

    // ---- out = Y @ out_w^T (split-K=2) ----
    split3<1><<<(DIM * (D_INNER / 4)) / 256, blk, 0, stream>>>(out_w, D_INNER, D_INNER, SCRB, DIM);
    gemm_mfma<0><<<dim3(DIM / 128, MROWS / 128, 2), blk, 0, stream>>>(
        SCRA, 3 * D_INNER, SCRB, 3 * D_INNER, OP, DIM, (size_t)MROWS * DIM, nullptr, (3 * D_INNER) / 2);
    reduce_out<<<(MROWS * DIM / 4) / 256, blk, 0, stream>>>(OP, out);
}

// Round 4
// 283.407 us; speedup vs baseline: 4.4104x; 1.3244x over previous
//
#include <hip/hip_runtime.h>
#include <hip/hip_bf16.h>
#include <stdint.h>

// Shapes
#define DIM      1024
#define D_STATE  16
#define D_CONV   4
#define D_INNER  2048
#define DT_RANK  64
#define BATCH    2
#define SEQ      1024
#define MROWS    (BATCH * SEQ)            // 2048
#define NPROJ    (2 * D_INNER)            // 4096
#define XDBL_K   (DT_RANK + 2 * D_STATE)  // 96

// chunked scan
#define LC       16
#define NC       (SEQ / LC)               // 64
#define SLANES   (BATCH * D_INNER * D_STATE) // 65536

typedef __attribute__((ext_vector_type(8))) short short8;
typedef __attribute__((ext_vector_type(4))) float f32x4;

__device__ __forceinline__ unsigned short f2bf(float f) {
    __hip_bfloat16 b = __float2bfloat16(f);
    return *reinterpret_cast<unsigned short*>(&b);
}
__device__ __forceinline__ float bf2f(unsigned short u) {
    __hip_bfloat16 b;
    *reinterpret_cast<unsigned short*>(&b) = u;
    return __bfloat162float(b);
}

__device__ __forceinline__ void gload_lds16(const unsigned short* g, unsigned short* l) {
    __builtin_amdgcn_global_load_lds(
        (const __attribute__((address_space(1))) void*)g,
        (__attribute__((address_space(3))) void*)l,
        16, 0, 0);
}

// ---------------------------------------------------------------------------
// 3-segment bf16 split. MODE 0 (A-side): [hi|hi|lo]. MODE 1 (B-side): [hi|lo|hi].
// ---------------------------------------------------------------------------
template <int MODE>
__global__ __launch_bounds__(256) void split3(
    const float* __restrict__ src, int lda, int K,
    unsigned short* __restrict__ dst, int rows_src)
{
    const int t = blockIdx.x * 256 + threadIdx.x;
    const int kq = K >> 2;
    const int r = t / kq;
    const int k4 = (t - r * kq) << 2;
    float4 v = make_float4(0.f, 0.f, 0.f, 0.f);
    if (r < rows_src)
        v = *reinterpret_cast<const float4*>(src + (size_t)r * lda + k4);
    const unsigned short h0 = f2bf(v.x), h1 = f2bf(v.y), h2 = f2bf(v.z), h3 = f2bf(v.w);
    const unsigned short l0 = f2bf(v.x - bf2f(h0)), l1 = f2bf(v.y - bf2f(h1));
    const unsigned short l2 = f2bf(v.z - bf2f(h2)), l3 = f2bf(v.w - bf2f(h3));
    const ushort4 hv = make_ushort4(h0, h1, h2, h3);
    const ushort4 lv = make_ushort4(l0, l1, l2, l3);
    unsigned short* dr = dst + (size_t)r * 3 * K + k4;
    *reinterpret_cast<ushort4*>(dr)         = hv;
    *reinterpret_cast<ushort4*>(dr + K)     = (MODE == 0) ? hv : lv;
    *reinterpret_cast<ushort4*>(dr + 2 * K) = (MODE == 0) ? lv : hv;
}

// ---------------------------------------------------------------------------
// bf16 MFMA GEMM (NT), 128x128 tile, BK=64, swizzled global_load_lds staging.
// ---------------------------------------------------------------------------
__device__ __forceinline__ short8 frag_ld(const unsigned short* base, int row, int slot) {
    const char* p = reinterpret_cast<const char*>(base) +
                    row * 128 + (((slot ^ (row & 7)) & 7) << 4);
    return *reinterpret_cast<const short8*>(p);
}

template <int EPI>
__global__ __launch_bounds__(256) void gemm_mfma(
    const unsigned short* __restrict__ A, int lda,
    const unsigned short* __restrict__ B, int ldb,
    float* __restrict__ C, int ldc, size_t czstride,
    const float* __restrict__ bias, int kLen)
{
    __shared__ unsigned short As[128 * 64];
    __shared__ unsigned short Bs[128 * 64];

    const int tid = threadIdx.x;
    const int lane = tid & 63;
    const int w = tid >> 6;
    const int wr = w >> 1, wc = w & 1;
    const int fr = lane & 15, fg = lane >> 4;
    const int m0 = blockIdx.y * 128;
    const int n0 = blockIdx.x * 128;
    const int kOff = blockIdx.z * kLen;
    A += kOff;
    B += kOff;
    C += (size_t)blockIdx.z * czstride;

    f32x4 zero = {0.f, 0.f, 0.f, 0.f};
    f32x4 acc[4][4];
#pragma unroll
    for (int i = 0; i < 4; ++i)
#pragma unroll
        for (int j = 0; j < 4; ++j) acc[i][j] = zero;

    for (int k0 = 0; k0 < kLen; k0 += 64) {
#pragma unroll
        for (int it = 0; it < 4; ++it) {
            const int f = it * 256 + tid;
            const int row = f >> 3;
            const int gc = ((f & 7) ^ (row & 7)) << 3;
            gload_lds16(A + (size_t)(m0 + row) * lda + k0 + gc, &As[f * 8]);
            gload_lds16(B + (size_t)(n0 + row) * ldb + k0 + gc, &Bs[f * 8]);
        }
        __syncthreads();
#pragma unroll
        for (int kk = 0; kk < 2; ++kk) {
            short8 af[4], bf_[4];
#pragma unroll
            for (int i = 0; i < 4; ++i) {
                af[i]  = frag_ld(As, wr * 64 + i * 16 + fr, kk * 4 + fg);
                bf_[i] = frag_ld(Bs, wc * 64 + i * 16 + fr, kk * 4 + fg);
            }
#pragma unroll
            for (int i = 0; i < 4; ++i)
#pragma unroll
                for (int j = 0; j < 4; ++j)
                    acc[i][j] = __builtin_amdgcn_mfma_f32_16x16x32_bf16(
                        af[i], bf_[j], acc[i][j], 0, 0, 0);
        }
        __syncthreads();
    }

#pragma unroll
    for (int i = 0; i < 4; ++i) {
        const int mrow = m0 + wr * 64 + i * 16 + fg * 4;
#pragma unroll
        for (int j = 0; j < 4; ++j) {
            const int col = n0 + wc * 64 + j * 16 + fr;
#pragma unroll
            for (int r = 0; r < 4; ++r) {
                float v = acc[i][j][r];
                if constexpr (EPI == 1) {
                    v += bias[col];
                    v = (v > 20.f) ? v : log1pf(__expf(v));
                }
                C[(size_t)(mrow + r) * ldc + col] = v;
            }
        }
    }
}

// ---------------------------------------------------------------------------
// Causal depthwise conv (k=4) + bias + SiLU; emits U (fp32) and split US.
// ---------------------------------------------------------------------------
__global__ __launch_bounds__(256) void conv_silu_split(
    const float* __restrict__ XR, const float* __restrict__ cw,
    const float* __restrict__ cb, float* __restrict__ U,
    unsigned short* __restrict__ US)
{
    const int idx = blockIdx.x * 256 + threadIdx.x;
    const int d = idx & (D_INNER - 1);
    const int m = idx >> 11;
    const int l = m & (SEQ - 1);

    float acc = cb[d];
#pragma unroll
    for (int j = 0; j < D_CONV; ++j) {
        const int ll = l - (D_CONV - 1) + j;
        if (ll >= 0)
            acc = fmaf(XR[(size_t)(m - (D_CONV - 1) + j) * NPROJ + d],
                       cw[d * D_CONV + j], acc);
    }
    const float s = acc / (1.f + __expf(-acc));
    U[idx] = s;
    const unsigned short h = f2bf(s);
    const unsigned short lo = f2bf(s - bf2f(h));
    const size_t rb = (size_t)m * (3 * D_INNER);
    US[rb + d] = h;
    US[rb + D_INNER + d] = h;
    US[rb + 2 * D_INNER + d] = lo;
}

// ---------------------------------------------------------------------------
// Chunked selective scan, lane = channel. Thread owns h[16], a[16] in regs.
// DELTA/U/res loads coalesced; B/C loads wave-uniform (scalar path).
// ---------------------------------------------------------------------------
__global__ __launch_bounds__(256) void scan_phase1(
    const float* __restrict__ DELTA, const float* __restrict__ U,
    const float* __restrict__ XDBL, const float* __restrict__ A_log,
    float* __restrict__ P, float* __restrict__ HL)
{
    const int tid = threadIdx.x;
    const int d = blockIdx.x * 256 + tid;
    const int c = blockIdx.y;
    const int b = blockIdx.z;

    float a[16];
#pragma unroll
    for (int q = 0; q < 4; ++q) {
        const float4 v = *reinterpret_cast<const float4*>(A_log + (size_t)d * 16 + q * 4);
        a[q * 4 + 0] = -__expf(v.x);
        a[q * 4 + 1] = -__expf(v.y);
        a[q * 4 + 2] = -__expf(v.z);
        a[q * 4 + 3] = -__expf(v.w);
    }
    float h[16];
#pragma unroll
    for (int n = 0; n < 16; ++n) h[n] = 0.f;
    float sd = 0.f;
    const size_t base = (size_t)b * SEQ + (size_t)c * LC;

#pragma unroll 4
    for (int t = 0; t < LC; ++t) {
        const size_t m = base + t;
        const float delta = DELTA[m * D_INNER + d];
        const float u = U[m * D_INNER + d];
        const float du = delta * u;
        const float* xb = XDBL + m * XDBL_K + DT_RANK;   // wave-uniform
        float bv[16];
#pragma unroll
        for (int n = 0; n < 16; ++n) bv[n] = xb[n];
        sd += delta;
#pragma unroll
        for (int n = 0; n < 16; ++n) {
            const float dA = __expf(delta * a[n]);
            h[n] = fmaf(dA, h[n], du * bv[n]);
        }
    }

    const size_t idx = (size_t)c * SLANES + ((size_t)b * D_INNER + d) * 16;
#pragma unroll
    for (int q = 0; q < 4; ++q) {
        float4 pv, hv;
        pv.x = __expf(a[q * 4 + 0] * sd);
        pv.y = __expf(a[q * 4 + 1] * sd);
        pv.z = __expf(a[q * 4 + 2] * sd);
        pv.w = __expf(a[q * 4 + 3] * sd);
        hv.x = h[q * 4 + 0]; hv.y = h[q * 4 + 1];
        hv.z = h[q * 4 + 2]; hv.w = h[q * 4 + 3];
        *reinterpret_cast<float4*>(&P[idx + q * 4]) = pv;
        *reinterpret_cast<float4*>(&HL[idx + q * 4]) = hv;
    }
}

__global__ __launch_bounds__(256) void scan_phase2(
    float* __restrict__ P, const float* __restrict__ HL)
{
    const int t = blockIdx.x * 256 + threadIdx.x;
    float h = 0.f;
#pragma unroll 4
    for (int c = 0; c < NC; ++c) {
        const size_t idx = (size_t)c * SLANES + t;
        const float p = P[idx];
        const float hl = HL[idx];
        P[idx] = h;
        h = fmaf(p, h, hl);
    }
}

__global__ __launch_bounds__(256) void scan_phase3(
    const float* __restrict__ DELTA, const float* __restrict__ U,
    const float* __restrict__ XDBL, const float* __restrict__ XR,
    const float* __restrict__ A_log, const float* __restrict__ Dp,
    const float* __restrict__ H0, unsigned short* __restrict__ YS)
{
    const int tid = threadIdx.x;
    const int d = blockIdx.x * 256 + tid;
    const int c = blockIdx.y;
    const int b = blockIdx.z;

    float a[16];
#pragma unroll
    for (int q = 0; q < 4; ++q) {
        const float4 v = *reinterpret_cast<const float4*>(A_log + (size_t)d * 16 + q * 4);
        a[q * 4 + 0] = -__expf(v.x);
        a[q * 4 + 1] = -__expf(v.y);
        a[q * 4 + 2] = -__expf(v.z);
        a[q * 4 + 3] = -__expf(v.w);
    }
    const float Dd = Dp[d];

    float h[16];
    const size_t idx0 = (size_t)c * SLANES + ((size_t)b * D_INNER + d) * 16;
#pragma unroll
    for (int q = 0; q < 4; ++q) {
        const float4 v = *reinterpret_cast<const float4*>(&H0[idx0 + q * 4]);
        h[q * 4 + 0] = v.x; h[q * 4 + 1] = v.y;
        h[q * 4 + 2] = v.z; h[q * 4 + 3] = v.w;
    }
    const size_t base = (size_t)b * SEQ + (size_t)c * LC;

#pragma unroll 4
    for (int t = 0; t < LC; ++t) {
        const size_t m = base + t;
        const float delta = DELTA[m * D_INNER + d];
        const float u = U[m * D_INNER + d];
        const float du = delta * u;
        const float* xb = XDBL + m * XDBL_K + DT_RANK;   // wave-uniform
        float bv[16], cv[16];
#pragma unroll
        for (int n = 0; n < 16; ++n) bv[n] = xb[n];
#pragma unroll
        for (int n = 0; n < 16; ++n) cv[n] = xb[16 + n];

        float y0 = 0.f, y1 = 0.f, y2 = 0.f, y3 = 0.f;
#pragma unroll
        for (int n = 0; n < 4; ++n) {
            const float dA0 = __expf(delta * a[n]);
            const float dA1 = __expf(delta * a[n + 4]);
            const float dA2 = __expf(delta * a[n + 8]);
            const float dA3 = __expf(delta * a[n + 12]);
            h[n]      = fmaf(dA0, h[n],      du * bv[n]);
            h[n + 4]  = fmaf(dA1, h[n + 4],  du * bv[n + 4]);
            h[n + 8]  = fmaf(dA2, h[n + 8],  du * bv[n + 8]);
            h[n + 12] = fmaf(dA3, h[n + 12], du * bv[n + 12]);
            y0 = fmaf(h[n],      cv[n],      y0);
            y1 = fmaf(h[n + 4],  cv[n + 4],  y1);
            y2 = fmaf(h[n + 8],  cv[n + 8],  y2);
            y3 = fmaf(h[n + 12], cv[n + 12], y3);
        }
        const float y = (y0 + y1) + (y2 + y3) + u * Dd;
        const float r = XR[m * NPROJ + D_INNER + d];
        const float sr = r / (1.f + __expf(-r));
        const float yg = y * sr;
        const unsigned short hh = f2bf(yg);
        const unsigned short lo = f2bf(yg - bf2f(hh));
        const size_t rb = m * (3 * D_INNER);
        YS[rb + d] = hh;
        YS[rb + D_INNER + d] = hh;
        YS[rb + 2 * D_INNER + d] = lo;
    }
}

// ---------------------------------------------------------------------------
// split-K reductions
// ---------------------------------------------------------------------------
__global__ __launch_bounds__(256) void reduce_xdbl(
    const float* __restrict__ PP, float* __restrict__ XDBL)
{
    const int t = blockIdx.x * 256 + threadIdx.x;
    const int m = t / XDBL_K;
    const int n = t - m * XDBL_K;
    float s = 0.f;
#pragma unroll
    for (int z = 0; z < 8; ++z)
        s += PP[(size_t)z * MROWS * 128 + (size_t)m * 128 + n];
    XDBL[t] = s;
}

__global__ __launch_bounds__(256) void reduce_out(
    const float* __restrict__ OP, float* __restrict__ out)
{
    const int t = blockIdx.x * 256 + threadIdx.x;
    const float4 a = *reinterpret_cast<const float4*>(OP + (size_t)t * 4);
    const float4 b = *reinterpret_cast<const float4*>(OP + (size_t)MROWS * DIM + (size_t)t * 4);
    float4 r;
    r.x = a.x + b.x; r.y = a.y + b.y; r.z = a.z + b.z; r.w = a.w + b.w;
    *reinterpret_cast<float4*>(out + (size_t)t * 4) = r;
}

// ---------------------------------------------------------------------------
extern "C" void kernel_launch(void* const* d_in, const int* in_sizes, int n_in,
                              void* d_out, int out_size, void* d_ws, size_t ws_size,
                              hipStream_t stream)
{
    const float* x       = (const float*)d_in[0];
    const float* in_w    = (const float*)d_in[1];
    const float* conv_w  = (const float*)d_in[2];
    const float* conv_b  = (const float*)d_in[3];
    const float* xproj_w = (const float*)d_in[4];
    const float* dt_w    = (const float*)d_in[5];
    const float* dt_b    = (const float*)d_in[6];
    const float* A_log   = (const float*)d_in[7];
    const float* Dp      = (const float*)d_in[8];
    const float* out_w   = (const float*)d_in[9];
    float* out = (float*)d_out;

    const size_t MF = 1024 * 1024;
    float* WF    = (float*)d_ws;
    // layout (floats):
    float* XR    = WF;                         // [0, 8M)   in_proj out; later OP at [0,4M)
    float* U     = WF + 8 * MF;                // [8M, 12M)
    float* DELTA = WF + 12 * MF;               // [12M, 16M); PP shares [12M,14M) earlier
    float* XDBL  = WF + 16 * MF;               // [16M, +192K)
    unsigned short* DS_A = (unsigned short*)(WF + (16 * MF + 256 * 1024));  // 384K ushorts
    unsigned short* DS_B = DS_A + (size_t)MROWS * 192;
    float* P     = WF + 17 * MF;               // [17M, 21M)
    float* HL    = WF + 21 * MF;               // [21M, 25M); later out_w split (3.1M floats)
    unsigned short* SCRA = (unsigned short*)(WF + 25 * MF);  // [25M, 31.5M) X/US/YS splits
    unsigned short* SCRB_BIG = (unsigned short*)(WF + 8 * MF);       // in_w split (step 1 only)
    unsigned short* SCRB_XP  = (unsigned short*)(WF + 31 * MF + 512 * 1024); // xproj split
    unsigned short* SCRB_OUT = (unsigned short*)HL;                  // out_w split (post-phase2)
    float* PP = WF + 12 * MF;
    float* OP = WF;

    const dim3 blk(256);

    // ---- in_proj: XR = X @ in_w^T ----
    split3<0><<<(MROWS * (DIM / 4)) / 256, blk, 0, stream>>>(x, DIM, DIM, SCRA, MROWS);
    split3<1><<<(NPROJ * (DIM / 4)) / 256, blk, 0, stream>>>(in_w, DIM, DIM, SCRB_BIG, NPROJ);
    gemm_mfma<0><<<dim3(NPROJ / 128, MROWS / 128, 1), blk, 0, stream>>>(
        SCRA, 3 * DIM, SCRB_BIG, 3 * DIM, XR, NPROJ, 0, nullptr, 3 * DIM);

    // ---- conv + silu ----
    conv_silu_split<<<(MROWS * D_INNER) / 256, blk, 0, stream>>>(XR, conv_w, conv_b, U, SCRA);

    // ---- x_dbl = U @ xproj_w^T (N 96->128, split-K=8) ----
    split3<1><<<(128 * (D_INNER / 4)) / 256, blk, 0, stream>>>(xproj_w, D_INNER, D_INNER, SCRB_XP, XDBL_K);
    gemm_mfma<0><<<dim3(1, MROWS / 128, 8), blk, 0, stream>>>(
        SCRA, 3 * D_INNER, SCRB_XP, 3 * D_INNER, PP, 128, (size_t)MROWS * 128, nullptr, (3 * D_INNER) / 8);
    reduce_xdbl<<<(MROWS * XDBL_K) / 256, blk, 0, stream>>>(PP, XDBL);

    // ---- DELTA = softplus(XDBL[:, :64] @ dt_w^T + dt_b) ----
    split3<0><<<(MROWS * (DT_RANK / 4)) / 256, blk, 0, stream>>>(XDBL, XDBL_K, DT_RANK, DS_A, MROWS);
    split3<1><<<(D_INNER * (DT_RANK / 4)) / 256, blk, 0, stream>>>(dt_w, DT_RANK, DT_RANK, DS_B, D_INNER);
    gemm_mfma<1><<<dim3(D_INNER / 128, MROWS / 128, 1), blk, 0, stream>>>(
        DS_A, 3 * DT_RANK, DS_B, 3 * DT_RANK, DELTA, D_INNER, 0, dt_b, 3 * DT_RANK);

    // ---- chunked selective scan ----
    scan_phase1<<<dim3(D_INNER / 256, NC, BATCH), blk, 0, stream>>>(
        DELTA, U, XDBL, A_log, P, HL);
    scan_phase2<<<SLANES / 256, blk, 0, stream>>>(P, HL);
    // out_w split placed in HL region (dead after phase2)
    split3<1><<<(DIM * (D_INNER / 4)) / 256, blk, 0, stream>>>(out_w, D_INNER, D_INNER, SCRB_OUT, DIM);
    scan_phase3<<<dim3(D_INNER / 256, NC, BATCH), blk, 0, stream>>>(
        DELTA, U, XDBL, XR, A_log, Dp, P, SCRA);

    // ---- out = Y @ out_w^T (split-K=2) ----
    gemm_mfma<0><<<dim3(DIM / 128, MROWS / 128, 2), blk, 0, stream>>>(
        SCRA, 3 * D_INNER, SCRB_OUT, 3 * D_INNER, OP, DIM, (size_t)MROWS * DIM, nullptr, (3 * D_INNER) / 2);
    reduce_out<<<(MROWS * DIM / 4) / 256, blk, 0, stream>>>(OP, out);
}

// Round 5
// 234.214 us; speedup vs baseline: 5.3368x; 1.2100x over previous
//
#include <hip/hip_runtime.h>
#include <hip/hip_bf16.h>
#include <stdint.h>

// Shapes
#define DIM      1024
#define D_STATE  16
#define D_CONV   4
#define D_INNER  2048
#define DT_RANK  64
#define BATCH    2
#define SEQ      1024
#define MROWS    (BATCH * SEQ)            // 2048
#define NPROJ    (2 * D_INNER)            // 4096
#define XDBL_K   (DT_RANK + 2 * D_STATE)  // 96

// chunked scan
#define LC       16
#define NC       (SEQ / LC)               // 64
#define SLANES   (BATCH * D_INNER * D_STATE) // 65536

typedef __attribute__((ext_vector_type(8))) short short8;
typedef __attribute__((ext_vector_type(4))) float f32x4;

__device__ __forceinline__ unsigned short f2bf(float f) {
    __hip_bfloat16 b = __float2bfloat16(f);
    return *reinterpret_cast<unsigned short*>(&b);
}
__device__ __forceinline__ float bf2f(unsigned short u) {
    __hip_bfloat16 b;
    *reinterpret_cast<unsigned short*>(&b) = u;
    return __bfloat162float(b);
}

// ---------------------------------------------------------------------------
// Fused-split bf16 MFMA GEMM (NT): C = A @ B^T, fp32 in, fp32 accum.
// Stages fp32 tiles, converts to bf16 hi/lo in-kernel (Ah/Al/Bh/Bl in LDS),
// computes AhBh + AhBl + AlBh per K-tile (BK=64). 128x128 tile, 4 waves.
// XOR-swizzled LDS (write & read sides match). blockIdx.z = split-K slice.
// EPI 1: softplus(C + bias[n]).
// ---------------------------------------------------------------------------
__device__ __forceinline__ short8 frag_ld(const unsigned short* base, int row, int slot) {
    const char* p = reinterpret_cast<const char*>(base) +
                    row * 128 + (((slot ^ (row & 7)) & 7) << 4);
    return *reinterpret_cast<const short8*>(p);
}

__device__ __forceinline__ void cvt8(const float4 v0, const float4 v1,
                                     short8& hi, short8& lo) {
    float f[8] = {v0.x, v0.y, v0.z, v0.w, v1.x, v1.y, v1.z, v1.w};
#pragma unroll
    for (int i = 0; i < 8; ++i) {
        const unsigned short h = f2bf(f[i]);
        hi[i] = (short)h;
        lo[i] = (short)f2bf(f[i] - bf2f(h));
    }
}

template <int EPI>
__global__ __launch_bounds__(256) void gemm3(
    const float* __restrict__ A, int lda,
    const float* __restrict__ B, int ldb, int nrowsB,
    float* __restrict__ C, int ldc, size_t czstride,
    const float* __restrict__ bias, int kLen)
{
    __shared__ unsigned short Ah[128 * 64];
    __shared__ unsigned short Al[128 * 64];
    __shared__ unsigned short Bh[128 * 64];
    __shared__ unsigned short Bl[128 * 64];

    const int tid = threadIdx.x;
    const int lane = tid & 63;
    const int w = tid >> 6;
    const int wr = w >> 1, wc = w & 1;
    const int fr = lane & 15, fg = lane >> 4;
    const int m0 = blockIdx.y * 128;
    const int n0 = blockIdx.x * 128;
    const int kOff = blockIdx.z * kLen;
    A += kOff;
    B += kOff;
    C += (size_t)blockIdx.z * czstride;

    f32x4 zero = {0.f, 0.f, 0.f, 0.f};
    f32x4 acc[4][4];
#pragma unroll
    for (int i = 0; i < 4; ++i)
#pragma unroll
        for (int j = 0; j < 4; ++j) acc[i][j] = zero;

    for (int k0 = 0; k0 < kLen; k0 += 64) {
        // stage: 1024 granules of 8 elems per matrix; thread -> (row, slot)
#pragma unroll
        for (int it = 0; it < 4; ++it) {
            const int g = it * 256 + tid;
            const int row = g >> 3;
            const int slot = g & 7;
            const int off = row * 64 + ((slot ^ (row & 7)) << 3);  // ushort units

            const float* sa = A + (size_t)(m0 + row) * lda + k0 + slot * 8;
            float4 a0 = *reinterpret_cast<const float4*>(sa);
            float4 a1 = *reinterpret_cast<const float4*>(sa + 4);
            short8 h, l;
            cvt8(a0, a1, h, l);
            *reinterpret_cast<short8*>(&Ah[off]) = h;
            *reinterpret_cast<short8*>(&Al[off]) = l;

            float4 b0 = make_float4(0.f, 0.f, 0.f, 0.f), b1 = b0;
            if (n0 + row < nrowsB) {
                const float* sb = B + (size_t)(n0 + row) * ldb + k0 + slot * 8;
                b0 = *reinterpret_cast<const float4*>(sb);
                b1 = *reinterpret_cast<const float4*>(sb + 4);
            }
            cvt8(b0, b1, h, l);
            *reinterpret_cast<short8*>(&Bh[off]) = h;
            *reinterpret_cast<short8*>(&Bl[off]) = l;
        }
        __syncthreads();

#pragma unroll
        for (int kk = 0; kk < 2; ++kk) {
            short8 ah[4], al[4], bh[4], bl[4];
#pragma unroll
            for (int i = 0; i < 4; ++i) {
                ah[i] = frag_ld(Ah, wr * 64 + i * 16 + fr, kk * 4 + fg);
                al[i] = frag_ld(Al, wr * 64 + i * 16 + fr, kk * 4 + fg);
                bh[i] = frag_ld(Bh, wc * 64 + i * 16 + fr, kk * 4 + fg);
                bl[i] = frag_ld(Bl, wc * 64 + i * 16 + fr, kk * 4 + fg);
            }
#pragma unroll
            for (int i = 0; i < 4; ++i)
#pragma unroll
                for (int j = 0; j < 4; ++j)
                    acc[i][j] = __builtin_amdgcn_mfma_f32_16x16x32_bf16(
                        ah[i], bh[j], acc[i][j], 0, 0, 0);
#pragma unroll
            for (int i = 0; i < 4; ++i)
#pragma unroll
                for (int j = 0; j < 4; ++j)
                    acc[i][j] = __builtin_amdgcn_mfma_f32_16x16x32_bf16(
                        ah[i], bl[j], acc[i][j], 0, 0, 0);
#pragma unroll
            for (int i = 0; i < 4; ++i)
#pragma unroll
                for (int j = 0; j < 4; ++j)
                    acc[i][j] = __builtin_amdgcn_mfma_f32_16x16x32_bf16(
                        al[i], bh[j], acc[i][j], 0, 0, 0);
        }
        __syncthreads();
    }

#pragma unroll
    for (int i = 0; i < 4; ++i) {
        const int mrow = m0 + wr * 64 + i * 16 + fg * 4;
#pragma unroll
        for (int j = 0; j < 4; ++j) {
            const int col = n0 + wc * 64 + j * 16 + fr;
#pragma unroll
            for (int r = 0; r < 4; ++r) {
                float v = acc[i][j][r];
                if constexpr (EPI == 1) {
                    v += bias[col];
                    v = (v > 20.f) ? v : log1pf(__expf(v));
                }
                C[(size_t)(mrow + r) * ldc + col] = v;
            }
        }
    }
}

// ---------------------------------------------------------------------------
// Causal depthwise conv (k=4) + bias + SiLU -> U (fp32).
// ---------------------------------------------------------------------------
__global__ __launch_bounds__(256) void conv_silu(
    const float* __restrict__ XR, const float* __restrict__ cw,
    const float* __restrict__ cb, float* __restrict__ U)
{
    const int idx = blockIdx.x * 256 + threadIdx.x;
    const int d = idx & (D_INNER - 1);
    const int m = idx >> 11;
    const int l = m & (SEQ - 1);

    float acc = cb[d];
#pragma unroll
    for (int j = 0; j < D_CONV; ++j) {
        const int ll = l - (D_CONV - 1) + j;
        if (ll >= 0)
            acc = fmaf(XR[(size_t)(m - (D_CONV - 1) + j) * NPROJ + d],
                       cw[d * D_CONV + j], acc);
    }
    U[idx] = acc / (1.f + __expf(-acc));
}

// ---------------------------------------------------------------------------
// Chunked selective scan, lane = channel; h[16], a[16] in regs.
// ---------------------------------------------------------------------------
__global__ __launch_bounds__(256) void scan_phase1(
    const float* __restrict__ DELTA, const float* __restrict__ U,
    const float* __restrict__ XDBL, const float* __restrict__ A_log,
    float* __restrict__ P, float* __restrict__ HL)
{
    const int tid = threadIdx.x;
    const int d = blockIdx.x * 256 + tid;
    const int c = blockIdx.y;
    const int b = blockIdx.z;

    float a[16];
#pragma unroll
    for (int q = 0; q < 4; ++q) {
        const float4 v = *reinterpret_cast<const float4*>(A_log + (size_t)d * 16 + q * 4);
        a[q * 4 + 0] = -__expf(v.x);
        a[q * 4 + 1] = -__expf(v.y);
        a[q * 4 + 2] = -__expf(v.z);
        a[q * 4 + 3] = -__expf(v.w);
    }
    float h[16];
#pragma unroll
    for (int n = 0; n < 16; ++n) h[n] = 0.f;
    float sd = 0.f;
    const size_t base = (size_t)b * SEQ + (size_t)c * LC;

#pragma unroll 4
    for (int t = 0; t < LC; ++t) {
        const size_t m = base + t;
        const float delta = DELTA[m * D_INNER + d];
        const float u = U[m * D_INNER + d];
        const float du = delta * u;
        const float* xb = XDBL + m * XDBL_K + DT_RANK;   // wave-uniform
        float bv[16];
#pragma unroll
        for (int n = 0; n < 16; ++n) bv[n] = xb[n];
        sd += delta;
#pragma unroll
        for (int n = 0; n < 16; ++n) {
            const float dA = __expf(delta * a[n]);
            h[n] = fmaf(dA, h[n], du * bv[n]);
        }
    }

    const size_t idx = (size_t)c * SLANES + ((size_t)b * D_INNER + d) * 16;
#pragma unroll
    for (int q = 0; q < 4; ++q) {
        float4 pv, hv;
        pv.x = __expf(a[q * 4 + 0] * sd);
        pv.y = __expf(a[q * 4 + 1] * sd);
        pv.z = __expf(a[q * 4 + 2] * sd);
        pv.w = __expf(a[q * 4 + 3] * sd);
        hv.x = h[q * 4 + 0]; hv.y = h[q * 4 + 1];
        hv.z = h[q * 4 + 2]; hv.w = h[q * 4 + 3];
        *reinterpret_cast<float4*>(&P[idx + q * 4]) = pv;
        *reinterpret_cast<float4*>(&HL[idx + q * 4]) = hv;
    }
}

__global__ __launch_bounds__(256) void scan_phase2(
    float* __restrict__ P, const float* __restrict__ HL)
{
    const int t = blockIdx.x * 256 + threadIdx.x;
    float h = 0.f;
#pragma unroll 4
    for (int c = 0; c < NC; ++c) {
        const size_t idx = (size_t)c * SLANES + t;
        const float p = P[idx];
        const float hl = HL[idx];
        P[idx] = h;
        h = fmaf(p, h, hl);
    }
}

__global__ __launch_bounds__(256) void scan_phase3(
    const float* __restrict__ DELTA, const float* __restrict__ U,
    const float* __restrict__ XDBL, const float* __restrict__ XR,
    const float* __restrict__ A_log, const float* __restrict__ Dp,
    const float* __restrict__ H0, float* __restrict__ Y)
{
    const int tid = threadIdx.x;
    const int d = blockIdx.x * 256 + tid;
    const int c = blockIdx.y;
    const int b = blockIdx.z;

    float a[16];
#pragma unroll
    for (int q = 0; q < 4; ++q) {
        const float4 v = *reinterpret_cast<const float4*>(A_log + (size_t)d * 16 + q * 4);
        a[q * 4 + 0] = -__expf(v.x);
        a[q * 4 + 1] = -__expf(v.y);
        a[q * 4 + 2] = -__expf(v.z);
        a[q * 4 + 3] = -__expf(v.w);
    }
    const float Dd = Dp[d];

    float h[16];
    const size_t idx0 = (size_t)c * SLANES + ((size_t)b * D_INNER + d) * 16;
#pragma unroll
    for (int q = 0; q < 4; ++q) {
        const float4 v = *reinterpret_cast<const float4*>(&H0[idx0 + q * 4]);
        h[q * 4 + 0] = v.x; h[q * 4 + 1] = v.y;
        h[q * 4 + 2] = v.z; h[q * 4 + 3] = v.w;
    }
    const size_t base = (size_t)b * SEQ + (size_t)c * LC;

#pragma unroll 4
    for (int t = 0; t < LC; ++t) {
        const size_t m = base + t;
        const float delta = DELTA[m * D_INNER + d];
        const float u = U[m * D_INNER + d];
        const float du = delta * u;
        const float* xb = XDBL + m * XDBL_K + DT_RANK;   // wave-uniform
        float bv[16], cv[16];
#pragma unroll
        for (int n = 0; n < 16; ++n) bv[n] = xb[n];
#pragma unroll
        for (int n = 0; n < 16; ++n) cv[n] = xb[16 + n];

        float y0 = 0.f, y1 = 0.f, y2 = 0.f, y3 = 0.f;
#pragma unroll
        for (int n = 0; n < 4; ++n) {
            const float dA0 = __expf(delta * a[n]);
            const float dA1 = __expf(delta * a[n + 4]);
            const float dA2 = __expf(delta * a[n + 8]);
            const float dA3 = __expf(delta * a[n + 12]);
            h[n]      = fmaf(dA0, h[n],      du * bv[n]);
            h[n + 4]  = fmaf(dA1, h[n + 4],  du * bv[n + 4]);
            h[n + 8]  = fmaf(dA2, h[n + 8],  du * bv[n + 8]);
            h[n + 12] = fmaf(dA3, h[n + 12], du * bv[n + 12]);
            y0 = fmaf(h[n],      cv[n],      y0);
            y1 = fmaf(h[n + 4],  cv[n + 4],  y1);
            y2 = fmaf(h[n + 8],  cv[n + 8],  y2);
            y3 = fmaf(h[n + 12], cv[n + 12], y3);
        }
        const float y = (y0 + y1) + (y2 + y3) + u * Dd;
        const float r = XR[m * NPROJ + D_INNER + d];
        const float sr = r / (1.f + __expf(-r));
        Y[m * D_INNER + d] = y * sr;
    }
}

// ---------------------------------------------------------------------------
// split-K reductions
// ---------------------------------------------------------------------------
__global__ __launch_bounds__(256) void reduce_xdbl(
    const float* __restrict__ PP, float* __restrict__ XDBL)
{
    const int t = blockIdx.x * 256 + threadIdx.x;
    const int m = t / XDBL_K;
    const int n = t - m * XDBL_K;
    float s = 0.f;
#pragma unroll
    for (int z = 0; z < 8; ++z)
        s += PP[(size_t)z * MROWS * 128 + (size_t)m * 128 + n];
    XDBL[t] = s;
}

__global__ __launch_bounds__(256) void reduce_out(
    const float* __restrict__ OP, float* __restrict__ out)
{
    const int t = blockIdx.x * 256 + threadIdx.x;
    float4 s = *reinterpret_cast<const float4*>(OP + (size_t)t * 4);
#pragma unroll
    for (int z = 1; z < 4; ++z) {
        const float4 v = *reinterpret_cast<const float4*>(
            OP + (size_t)z * MROWS * DIM + (size_t)t * 4);
        s.x += v.x; s.y += v.y; s.z += v.z; s.w += v.w;
    }
    *reinterpret_cast<float4*>(out + (size_t)t * 4) = s;
}

// ---------------------------------------------------------------------------
extern "C" void kernel_launch(void* const* d_in, const int* in_sizes, int n_in,
                              void* d_out, int out_size, void* d_ws, size_t ws_size,
                              hipStream_t stream)
{
    const float* x       = (const float*)d_in[0];
    const float* in_w    = (const float*)d_in[1];
    const float* conv_w  = (const float*)d_in[2];
    const float* conv_b  = (const float*)d_in[3];
    const float* xproj_w = (const float*)d_in[4];
    const float* dt_w    = (const float*)d_in[5];
    const float* dt_b    = (const float*)d_in[6];
    const float* A_log   = (const float*)d_in[7];
    const float* Dp      = (const float*)d_in[8];
    const float* out_w   = (const float*)d_in[9];
    float* out = (float*)d_out;

    const size_t MF = 1024 * 1024;
    float* WF    = (float*)d_ws;
    float* XR    = WF;                         // [0, 8M)   in_proj out; later OP
    float* U     = WF + 8 * MF;                // [8M, 12M)
    float* DELTA = WF + 12 * MF;               // [12M, 16M); PP shares first 2M pre-DELTA
    float* XDBL  = WF + 16 * MF;               // [16M, +192K)
    float* P     = WF + 17 * MF;               // [17M, 21M)
    float* HL    = WF + 21 * MF;               // [21M, 25M)
    float* Y     = WF + 25 * MF;               // [25M, 29M)
    float* PP    = WF + 12 * MF;               // xdbl partials (dead before DELTA write)
    float* OP    = WF;                         // out partials (XR dead after phase3)

    const dim3 blk(256);

    // ---- in_proj: XR = X @ in_w^T (K=1024) ----
    gemm3<0><<<dim3(NPROJ / 128, MROWS / 128, 1), blk, 0, stream>>>(
        x, DIM, in_w, DIM, NPROJ, XR, NPROJ, 0, nullptr, DIM);

    // ---- conv + silu -> U ----
    conv_silu<<<(MROWS * D_INNER) / 256, blk, 0, stream>>>(XR, conv_w, conv_b, U);

    // ---- x_dbl = U @ xproj_w^T (N 96->128 pad, split-K=8, kLen=256) ----
    gemm3<0><<<dim3(1, MROWS / 128, 8), blk, 0, stream>>>(
        U, D_INNER, xproj_w, D_INNER, XDBL_K, PP, 128, (size_t)MROWS * 128, nullptr, D_INNER / 8);
    reduce_xdbl<<<(MROWS * XDBL_K) / 256, blk, 0, stream>>>(PP, XDBL);

    // ---- DELTA = softplus(XDBL[:, :64] @ dt_w^T + dt_b) (K=64) ----
    gemm3<1><<<dim3(D_INNER / 128, MROWS / 128, 1), blk, 0, stream>>>(
        XDBL, XDBL_K, dt_w, DT_RANK, D_INNER, DELTA, D_INNER, 0, dt_b, DT_RANK);

    // ---- chunked selective scan ----
    scan_phase1<<<dim3(D_INNER / 256, NC, BATCH), blk, 0, stream>>>(
        DELTA, U, XDBL, A_log, P, HL);
    scan_phase2<<<SLANES / 256, blk, 0, stream>>>(P, HL);
    scan_phase3<<<dim3(D_INNER / 256, NC, BATCH), blk, 0, stream>>>(
        DELTA, U, XDBL, XR, A_log, Dp, P, Y);

    // ---- out = Y @ out_w^T (split-K=4, kLen=512) ----
    gemm3<0><<<dim3(DIM / 128, MROWS / 128, 4), blk, 0, stream>>>(
        Y, D_INNER, out_w, D_INNER, DIM, OP, DIM, (size_t)MROWS * DIM, nullptr, D_INNER / 4);
    reduce_out<<<(MROWS * DIM / 4) / 256, blk, 0, stream>>>(OP, out);
}

// Round 7
// 228.300 us; speedup vs baseline: 5.4750x; 1.0259x over previous
//
#include <hip/hip_runtime.h>
#include <hip/hip_bf16.h>
#include <stdint.h>

// Shapes
#define DIM      1024
#define D_STATE  16
#define D_CONV   4
#define D_INNER  2048
#define DT_RANK  64
#define BATCH    2
#define SEQ      1024
#define MROWS    (BATCH * SEQ)            // 2048
#define NPROJ    (2 * D_INNER)            // 4096
#define XDBL_K   (DT_RANK + 2 * D_STATE)  // 96

// chunked scan
#define LC       16
#define NC       (SEQ / LC)               // 64
#define SLANES   (BATCH * D_INNER * D_STATE) // 65536

typedef __attribute__((ext_vector_type(8))) short short8;
typedef __attribute__((ext_vector_type(4))) float f32x4;
typedef unsigned short ushort_t;

__device__ __forceinline__ unsigned short f2bf(float f) {
    __hip_bfloat16 b = __float2bfloat16(f);
    return *reinterpret_cast<unsigned short*>(&b);
}
__device__ __forceinline__ float bf2f(unsigned short u) {
    __hip_bfloat16 b;
    *reinterpret_cast<unsigned short*>(&b) = u;
    return __bfloat162float(b);
}

__device__ __forceinline__ void gload_lds16(const unsigned short* g, unsigned short* l) {
    __builtin_amdgcn_global_load_lds(
        (const __attribute__((address_space(1))) void*)g,
        (__attribute__((address_space(3))) void*)l,
        16, 0, 0);
}

// ---------------------------------------------------------------------------
// Preamble: split all fp32 GEMM operand tensors into planar bf16 hi/lo.
// ---------------------------------------------------------------------------
#define SG0 524288    // x        granules (K/4 per row)
#define SG1 1048576   // in_w
#define SG2 65536     // xproj (128 rows pad)
#define SG3 32768     // dt_w
#define SG4 524288    // out_w
#define SPLIT_GRANULES (SG0 + SG1 + SG2 + SG3 + SG4)   // 2195456

__global__ __launch_bounds__(256) void split_all(
    const float* __restrict__ x,   const float* __restrict__ in_w,
    const float* __restrict__ xpw, const float* __restrict__ dtw,
    const float* __restrict__ ow,
    ushort_t* __restrict__ xh,   ushort_t* __restrict__ xl,
    ushort_t* __restrict__ iwh,  ushort_t* __restrict__ iwl,
    ushort_t* __restrict__ xph,  ushort_t* __restrict__ xpl,
    ushort_t* __restrict__ dth,  ushort_t* __restrict__ dtl,
    ushort_t* __restrict__ owh,  ushort_t* __restrict__ owl)
{
    int g = blockIdx.x * 256 + threadIdx.x;
    const float* src; int K, rows_src; ushort_t *dh, *dl;
    if (g < SG0)                      { src = x;    K = 1024; rows_src = 2048; dh = xh;  dl = xl; }
    else if ((g -= SG0) < SG1)        { src = in_w; K = 1024; rows_src = 4096; dh = iwh; dl = iwl; }
    else if ((g -= SG1) < SG2)        { src = xpw;  K = 2048; rows_src = 96;   dh = xph; dl = xpl; }
    else if ((g -= SG2) < SG3)        { src = dtw;  K = 64;   rows_src = 2048; dh = dth; dl = dtl; }
    else                              { g -= SG3;   src = ow; K = 2048; rows_src = 1024; dh = owh; dl = owl; }

    const int kq = K >> 2;
    const int r = g / kq;
    const int k4 = (g - r * kq) << 2;
    float4 v = make_float4(0.f, 0.f, 0.f, 0.f);
    if (r < rows_src)
        v = *reinterpret_cast<const float4*>(src + (size_t)r * K + k4);
    const unsigned short h0 = f2bf(v.x), h1 = f2bf(v.y), h2 = f2bf(v.z), h3 = f2bf(v.w);
    const unsigned short l0 = f2bf(v.x - bf2f(h0)), l1 = f2bf(v.y - bf2f(h1));
    const unsigned short l2 = f2bf(v.z - bf2f(h2)), l3 = f2bf(v.w - bf2f(h3));
    *reinterpret_cast<ushort4*>(dh + (size_t)r * K + k4) = make_ushort4(h0, h1, h2, h3);
    *reinterpret_cast<ushort4*>(dl + (size_t)r * K + k4) = make_ushort4(l0, l1, l2, l3);
}

// ---------------------------------------------------------------------------
// Planar 3-pass bf16 MFMA GEMM (NT): C = A @ B^T, fp32 accum.
// AhBh + AhBl + AlBh. 128x128 tile, BK=64, 4 waves, global_load_lds(16B)
// staging with pre-swizzled source cols; XOR-swizzled ds_read_b128.
// ---------------------------------------------------------------------------
__device__ __forceinline__ short8 frag_ld(const unsigned short* base, int row, int slot) {
    const char* p = reinterpret_cast<const char*>(base) +
                    row * 128 + (((slot ^ (row & 7)) & 7) << 4);
    return *reinterpret_cast<const short8*>(p);
}

template <int EPI>
__global__ __launch_bounds__(256) void gemm_bf3(
    const ushort_t* __restrict__ Ahg, const ushort_t* __restrict__ Alg, int lda,
    const ushort_t* __restrict__ Bhg, const ushort_t* __restrict__ Blg, int ldb,
    float* __restrict__ C, int ldc, size_t czstride,
    const float* __restrict__ bias, int kLen)
{
    __shared__ unsigned short Ahs[128 * 64];
    __shared__ unsigned short Als[128 * 64];
    __shared__ unsigned short Bhs[128 * 64];
    __shared__ unsigned short Bls[128 * 64];

    const int tid = threadIdx.x;
    const int lane = tid & 63;
    const int w = tid >> 6;
    const int wr = w >> 1, wc = w & 1;
    const int fr = lane & 15, fg = lane >> 4;
    const int m0 = blockIdx.y * 128;
    const int n0 = blockIdx.x * 128;
    const int kOff = blockIdx.z * kLen;
    Ahg += kOff; Alg += kOff; Bhg += kOff; Blg += kOff;
    C += (size_t)blockIdx.z * czstride;

    f32x4 zero = {0.f, 0.f, 0.f, 0.f};
    f32x4 acc[4][4];
#pragma unroll
    for (int i = 0; i < 4; ++i)
#pragma unroll
        for (int j = 0; j < 4; ++j) acc[i][j] = zero;

    for (int k0 = 0; k0 < kLen; k0 += 64) {
#pragma unroll
        for (int it = 0; it < 4; ++it) {
            const int f = it * 256 + tid;
            const int row = f >> 3;
            const int gc = ((f & 7) ^ (row & 7)) << 3;   // pre-swizzled source col
            const size_t ga = (size_t)(m0 + row) * lda + k0 + gc;
            const size_t gb = (size_t)(n0 + row) * ldb + k0 + gc;
            gload_lds16(Ahg + ga, &Ahs[f * 8]);
            gload_lds16(Alg + ga, &Als[f * 8]);
            gload_lds16(Bhg + gb, &Bhs[f * 8]);
            gload_lds16(Blg + gb, &Bls[f * 8]);
        }
        __syncthreads();

#pragma unroll
        for (int kk = 0; kk < 2; ++kk) {
            short8 ah[4], bh[4], xf[4];
#pragma unroll
            for (int i = 0; i < 4; ++i) {
                ah[i] = frag_ld(Ahs, wr * 64 + i * 16 + fr, kk * 4 + fg);
                bh[i] = frag_ld(Bhs, wc * 64 + i * 16 + fr, kk * 4 + fg);
            }
#pragma unroll
            for (int i = 0; i < 4; ++i)
#pragma unroll
                for (int j = 0; j < 4; ++j)
                    acc[i][j] = __builtin_amdgcn_mfma_f32_16x16x32_bf16(
                        ah[i], bh[j], acc[i][j], 0, 0, 0);
            // bl pass
#pragma unroll
            for (int i = 0; i < 4; ++i)
                xf[i] = frag_ld(Bls, wc * 64 + i * 16 + fr, kk * 4 + fg);
#pragma unroll
            for (int i = 0; i < 4; ++i)
#pragma unroll
                for (int j = 0; j < 4; ++j)
                    acc[i][j] = __builtin_amdgcn_mfma_f32_16x16x32_bf16(
                        ah[i], xf[j], acc[i][j], 0, 0, 0);
            // al pass
#pragma unroll
            for (int i = 0; i < 4; ++i)
                xf[i] = frag_ld(Als, wr * 64 + i * 16 + fr, kk * 4 + fg);
#pragma unroll
            for (int i = 0; i < 4; ++i)
#pragma unroll
                for (int j = 0; j < 4; ++j)
                    acc[i][j] = __builtin_amdgcn_mfma_f32_16x16x32_bf16(
                        xf[i], bh[j], acc[i][j], 0, 0, 0);
        }
        __syncthreads();
    }

#pragma unroll
    for (int i = 0; i < 4; ++i) {
        const int mrow = m0 + wr * 64 + i * 16 + fg * 4;
#pragma unroll
        for (int j = 0; j < 4; ++j) {
            const int col = n0 + wc * 64 + j * 16 + fr;
#pragma unroll
            for (int r = 0; r < 4; ++r) {
                float v = acc[i][j][r];
                if constexpr (EPI == 1) {
                    v += bias[col];
                    v = (v > 20.f) ? v : log1pf(__expf(v));
                }
                C[(size_t)(mrow + r) * ldc + col] = v;
            }
        }
    }
}

// ---------------------------------------------------------------------------
// Causal depthwise conv (k=4) + bias + SiLU -> planar Uh/Ul.
// ---------------------------------------------------------------------------
__global__ __launch_bounds__(256) void conv_silu(
    const float* __restrict__ XR, const float* __restrict__ cw,
    const float* __restrict__ cb, ushort_t* __restrict__ Uh,
    ushort_t* __restrict__ Ul)
{
    const int idx = blockIdx.x * 256 + threadIdx.x;
    const int d = idx & (D_INNER - 1);
    const int m = idx >> 11;
    const int l = m & (SEQ - 1);

    float acc = cb[d];
#pragma unroll
    for (int j = 0; j < D_CONV; ++j) {
        const int ll = l - (D_CONV - 1) + j;
        if (ll >= 0)
            acc = fmaf(XR[(size_t)(m - (D_CONV - 1) + j) * NPROJ + d],
                       cw[d * D_CONV + j], acc);
    }
    const float s = acc / (1.f + __expf(-acc));
    const unsigned short h = f2bf(s);
    Uh[idx] = h;
    Ul[idx] = f2bf(s - bf2f(h));
}

// ---------------------------------------------------------------------------
// Chunked selective scan, lane = channel; h[16], a[16] in regs.
// ---------------------------------------------------------------------------
__global__ __launch_bounds__(256) void scan_phase1(
    const float* __restrict__ DELTA, const ushort_t* __restrict__ Uh,
    const ushort_t* __restrict__ Ul, const float* __restrict__ XDBL,
    const float* __restrict__ A_log, float* __restrict__ P,
    float* __restrict__ HL)
{
    const int tid = threadIdx.x;
    const int d = blockIdx.x * 256 + tid;
    const int c = blockIdx.y;
    const int b = blockIdx.z;

    float a[16];
#pragma unroll
    for (int q = 0; q < 4; ++q) {
        const float4 v = *reinterpret_cast<const float4*>(A_log + (size_t)d * 16 + q * 4);
        a[q * 4 + 0] = -__expf(v.x);
        a[q * 4 + 1] = -__expf(v.y);
        a[q * 4 + 2] = -__expf(v.z);
        a[q * 4 + 3] = -__expf(v.w);
    }
    float h[16];
#pragma unroll
    for (int n = 0; n < 16; ++n) h[n] = 0.f;
    float sd = 0.f;
    const size_t base = (size_t)b * SEQ + (size_t)c * LC;

#pragma unroll 4
    for (int t = 0; t < LC; ++t) {
        const size_t m = base + t;
        const float delta = DELTA[m * D_INNER + d];
        const float u = bf2f(Uh[m * D_INNER + d]) + bf2f(Ul[m * D_INNER + d]);
        const float du = delta * u;
        const float* xb = XDBL + m * XDBL_K + DT_RANK;   // wave-uniform
        float bv[16];
#pragma unroll
        for (int n = 0; n < 16; ++n) bv[n] = xb[n];
        sd += delta;
#pragma unroll
        for (int n = 0; n < 16; ++n) {
            const float dA = __expf(delta * a[n]);
            h[n] = fmaf(dA, h[n], du * bv[n]);
        }
    }

    const size_t idx = (size_t)c * SLANES + ((size_t)b * D_INNER + d) * 16;
#pragma unroll
    for (int q = 0; q < 4; ++q) {
        float4 pv, hv;
        pv.x = __expf(a[q * 4 + 0] * sd);
        pv.y = __expf(a[q * 4 + 1] * sd);
        pv.z = __expf(a[q * 4 + 2] * sd);
        pv.w = __expf(a[q * 4 + 3] * sd);
        hv.x = h[q * 4 + 0]; hv.y = h[q * 4 + 1];
        hv.z = h[q * 4 + 2]; hv.w = h[q * 4 + 3];
        *reinterpret_cast<float4*>(&P[idx + q * 4]) = pv;
        *reinterpret_cast<float4*>(&HL[idx + q * 4]) = hv;
    }
}

__global__ __launch_bounds__(256) void scan_phase2(
    float* __restrict__ P, const float* __restrict__ HL)
{
    const int t = blockIdx.x * 256 + threadIdx.x;
    float h = 0.f;
#pragma unroll 4
    for (int c = 0; c < NC; ++c) {
        const size_t idx = (size_t)c * SLANES + t;
        const float p = P[idx];
        const float hl = HL[idx];
        P[idx] = h;
        h = fmaf(p, h, hl);
    }
}

__global__ __launch_bounds__(256) void scan_phase3(
    const float* __restrict__ DELTA, const ushort_t* __restrict__ Uh,
    const ushort_t* __restrict__ Ul, const float* __restrict__ XDBL,
    const float* __restrict__ XR, const float* __restrict__ A_log,
    const float* __restrict__ Dp, const float* __restrict__ H0,
    ushort_t* __restrict__ Yh, ushort_t* __restrict__ Yl)
{
    const int tid = threadIdx.x;
    const int d = blockIdx.x * 256 + tid;
    const int c = blockIdx.y;
    const int b = blockIdx.z;

    float a[16];
#pragma unroll
    for (int q = 0; q < 4; ++q) {
        const float4 v = *reinterpret_cast<const float4*>(A_log + (size_t)d * 16 + q * 4);
        a[q * 4 + 0] = -__expf(v.x);
        a[q * 4 + 1] = -__expf(v.y);
        a[q * 4 + 2] = -__expf(v.z);
        a[q * 4 + 3] = -__expf(v.w);
    }
    const float Dd = Dp[d];

    float h[16];
    const size_t idx0 = (size_t)c * SLANES + ((size_t)b * D_INNER + d) * 16;
#pragma unroll
    for (int q = 0; q < 4; ++q) {
        const float4 v = *reinterpret_cast<const float4*>(&H0[idx0 + q * 4]);
        h[q * 4 + 0] = v.x; h[q * 4 + 1] = v.y;
        h[q * 4 + 2] = v.z; h[q * 4 + 3] = v.w;
    }
    const size_t base = (size_t)b * SEQ + (size_t)c * LC;

#pragma unroll 4
    for (int t = 0; t < LC; ++t) {
        const size_t m = base + t;
        const float delta = DELTA[m * D_INNER + d];
        const float u = bf2f(Uh[m * D_INNER + d]) + bf2f(Ul[m * D_INNER + d]);
        const float du = delta * u;
        const float* xb = XDBL + m * XDBL_K + DT_RANK;   // wave-uniform
        float bv[16], cv[16];
#pragma unroll
        for (int n = 0; n < 16; ++n) bv[n] = xb[n];
#pragma unroll
        for (int n = 0; n < 16; ++n) cv[n] = xb[16 + n];

        float y0 = 0.f, y1 = 0.f, y2 = 0.f, y3 = 0.f;
#pragma unroll
        for (int n = 0; n < 4; ++n) {
            const float dA0 = __expf(delta * a[n]);
            const float dA1 = __expf(delta * a[n + 4]);
            const float dA2 = __expf(delta * a[n + 8]);
            const float dA3 = __expf(delta * a[n + 12]);
            h[n]      = fmaf(dA0, h[n],      du * bv[n]);
            h[n + 4]  = fmaf(dA1, h[n + 4],  du * bv[n + 4]);
            h[n + 8]  = fmaf(dA2, h[n + 8],  du * bv[n + 8]);
            h[n + 12] = fmaf(dA3, h[n + 12], du * bv[n + 12]);
            y0 = fmaf(h[n],      cv[n],      y0);
            y1 = fmaf(h[n + 4],  cv[n + 4],  y1);
            y2 = fmaf(h[n + 8],  cv[n + 8],  y2);
            y3 = fmaf(h[n + 12], cv[n + 12], y3);
        }
        const float y = (y0 + y1) + (y2 + y3) + u * Dd;
        const float r = XR[m * NPROJ + D_INNER + d];
        const float sr = r / (1.f + __expf(-r));
        const float yg = y * sr;
        const unsigned short hh = f2bf(yg);
        Yh[m * D_INNER + d] = hh;
        Yl[m * D_INNER + d] = f2bf(yg - bf2f(hh));
    }
}

// ---------------------------------------------------------------------------
// split-K reductions
// ---------------------------------------------------------------------------
__global__ __launch_bounds__(256) void reduce_xdbl(
    const float* __restrict__ PP, float* __restrict__ XDBL,
    ushort_t* __restrict__ XDh, ushort_t* __restrict__ XDl)
{
    const int t = blockIdx.x * 256 + threadIdx.x;
    const int m = t / XDBL_K;
    const int n = t - m * XDBL_K;
    float s = 0.f;
#pragma unroll
    for (int z = 0; z < 8; ++z)
        s += PP[(size_t)z * MROWS * 128 + (size_t)m * 128 + n];
    XDBL[t] = s;
    if (n < DT_RANK) {
        const unsigned short h = f2bf(s);
        XDh[(size_t)m * DT_RANK + n] = h;
        XDl[(size_t)m * DT_RANK + n] = f2bf(s - bf2f(h));
    }
}

__global__ __launch_bounds__(256) void reduce_out(
    const float* __restrict__ OP, float* __restrict__ out)
{
    const int t = blockIdx.x * 256 + threadIdx.x;
    const float4 a = *reinterpret_cast<const float4*>(OP + (size_t)t * 4);
    const float4 b = *reinterpret_cast<const float4*>(OP + (size_t)MROWS * DIM + (size_t)t * 4);
    float4 r;
    r.x = a.x + b.x; r.y = a.y + b.y; r.z = a.z + b.z; r.w = a.w + b.w;
    *reinterpret_cast<float4*>(out + (size_t)t * 4) = r;
}

// ---------------------------------------------------------------------------
extern "C" void kernel_launch(void* const* d_in, const int* in_sizes, int n_in,
                              void* d_out, int out_size, void* d_ws, size_t ws_size,
                              hipStream_t stream)
{
    const float* x       = (const float*)d_in[0];
    const float* in_w    = (const float*)d_in[1];
    const float* conv_w  = (const float*)d_in[2];
    const float* conv_b  = (const float*)d_in[3];
    const float* xproj_w = (const float*)d_in[4];
    const float* dt_w    = (const float*)d_in[5];
    const float* dt_b    = (const float*)d_in[6];
    const float* A_log   = (const float*)d_in[7];
    const float* Dp      = (const float*)d_in[8];
    const float* out_w   = (const float*)d_in[9];
    float* out = (float*)d_out;

    const size_t MF = 1024 * 1024;
    float* WF    = (float*)d_ws;
    float* XR    = WF;                 // [0,8M) in_proj out; OP reuses [0,4M) after scan3
    float* DELTA = WF + 8 * MF;        // [8,12M); PP shares this region pre-DELTA
    float* XDBL  = WF + 12 * MF;       // 2048*96 floats
    float* P     = WF + 13 * MF;       // [13,17M)
    float* HL    = WF + 17 * MF;       // [17,21M); Yl reuses [17,19M) after phase2
    float* PP    = WF + 8 * MF;        // xdbl partials (dead before DELTA written)
    float* OP    = WF;                 // out partials (XR dead after phase3)

    // bf16 planar buffers (ushort units), base at 21M floats
    ushort_t* UB  = (ushort_t*)(WF + 21 * MF);
    ushort_t* xh  = UB;                         // 2M   } dead after in_proj:
    ushort_t* xl  = UB + 2 * MF;                // 2M   }  reused by Uh/Ul/Yh
    ushort_t* iwh = UB + 4 * MF;                // 4M   }
    ushort_t* iwl = UB + 8 * MF;                // 4M   }
    ushort_t* Uh  = UB;                         // 4M (conv output, 2048x2048)
    ushort_t* Ul  = UB + 4 * MF;                // 4M
    ushort_t* Yh  = UB + 8 * MF;                // 4M (scan3 output, 2048x2048)
    ushort_t* Yl  = (ushort_t*)(WF + 17 * MF);  // 4M ushorts in dead HL region
    ushort_t* xph = UB + 12 * MF;               // 256K (128 x 2048, padded)
    ushort_t* xpl = xph + 256 * 1024;           // 256K
    ushort_t* dth = xpl + 256 * 1024;           // 128K
    ushort_t* dtl = dth + 128 * 1024;           // 128K
    ushort_t* owh = dtl + 128 * 1024;           // 2M
    ushort_t* owl = owh + 2 * MF;               // 2M
    ushort_t* XDh = owl + 2 * MF;               // 128K
    ushort_t* XDl = XDh + 128 * 1024;           // 128K

    const dim3 blk(256);

    // 0) split all GEMM operands to planar bf16 hi/lo
    split_all<<<SPLIT_GRANULES / 256, blk, 0, stream>>>(
        x, in_w, xproj_w, dt_w, out_w,
        xh, xl, iwh, iwl, xph, xpl, dth, dtl, owh, owl);

    // 1) in_proj: XR = X @ in_w^T (K=1024)
    gemm_bf3<0><<<dim3(NPROJ / 128, MROWS / 128, 1), blk, 0, stream>>>(
        xh, xl, DIM, iwh, iwl, DIM, XR, NPROJ, 0, nullptr, DIM);

    // 2) conv + silu -> Uh/Ul
    conv_silu<<<(MROWS * D_INNER) / 256, blk, 0, stream>>>(XR, conv_w, conv_b, Uh, Ul);

    // 3) x_dbl = U @ xproj_w^T (N 96->128 pad, split-K=8, kLen=256)
    gemm_bf3<0><<<dim3(1, MROWS / 128, 8), blk, 0, stream>>>(
        Uh, Ul, D_INNER, xph, xpl, D_INNER, PP, 128, (size_t)MROWS * 128, nullptr, D_INNER / 8);
    reduce_xdbl<<<(MROWS * XDBL_K) / 256, blk, 0, stream>>>(PP, XDBL, XDh, XDl);

    // 4) DELTA = softplus(XDBL[:, :64] @ dt_w^T + dt_b) (K=64)
    gemm_bf3<1><<<dim3(D_INNER / 128, MROWS / 128, 1), blk, 0, stream>>>(
        XDh, XDl, DT_RANK, dth, dtl, DT_RANK, DELTA, D_INNER, 0, dt_b, DT_RANK);

    // 5) chunked selective scan
    scan_phase1<<<dim3(D_INNER / 256, NC, BATCH), blk, 0, stream>>>(
        DELTA, Uh, Ul, XDBL, A_log, P, HL);
    scan_phase2<<<SLANES / 256, blk, 0, stream>>>(P, HL);
    scan_phase3<<<dim3(D_INNER / 256, NC, BATCH), blk, 0, stream>>>(
        DELTA, Uh, Ul, XDBL, XR, A_log, Dp, P, Yh, Yl);

    // 6) out = Y @ out_w^T (split-K=2, kLen=1024)
    gemm_bf3<0><<<dim3(DIM / 128, MROWS / 128, 2), blk, 0, stream>>>(
        Yh, Yl, D_INNER, owh, owl, D_INNER, OP, DIM, (size_t)MROWS * DIM, nullptr, D_INNER / 2);
    reduce_out<<<(MROWS * DIM / 4) / 256, blk, 0, stream>>>(OP, out);
}